// Round 2
// baseline (637.629 us; speedup 1.0000x reference)
//
#include <hip/hip_runtime.h>
#include <math.h>

// ---------------- workspace layout (float offsets) ----------------
constexpr size_t X_OFF    = 0;               // 4096*290
constexpr size_t WP_OFF   = 1187840;         // 290*256
constexpr size_t BP_OFF   = 1262080;         // 256
constexpr size_t P_OFF    = 1262336;         // 4096*256
constexpr size_t WF_OFF   = 2310912;         // 72*64 (t0@0,t1@1024,t2@2560)
constexpr size_t WQKV_OFF = 2315520;         // 3*64*64
constexpr size_t WO_OFF   = 2327808;         // 64*64
constexpr size_t WSA_OFF  = 2331904;         // 64*64
constexpr size_t Y_OFF    = 2336000;         // 4096*64   (z_pool)
constexpr size_t PW_OFF   = 2598144;         // 354*128
constexpr size_t Z_OFF    = 2643456;         // 4096*128
constexpr size_t WIH_OFF  = 3167744;         // 128*512
constexpr size_t BG_OFF   = 3233280;         // 512
constexpr size_t GX_OFF   = 3233792;         // 4096*512
// total 5,330,944 floats = 21.3 MB

static __device__ __forceinline__ float sigf(float x) { return 1.0f / (1.0f + __expf(-x)); }

// ---------------- prep: fold & transpose weights ----------------
__global__ __launch_bounds__(256) void k_prep(
    const float* __restrict__ self_w, const float* __restrict__ self_b,
    const float* __restrict__ e0w, const float* __restrict__ e0b,
    const float* __restrict__ e1w, const float* __restrict__ e1b,
    const float* __restrict__ e2w, const float* __restrict__ e2b,
    const float* __restrict__ ipw, const float* __restrict__ opw,
    const float* __restrict__ saw, const float* __restrict__ plw,
    const float* __restrict__ wih, const float* __restrict__ bih,
    const float* __restrict__ bhh, float* __restrict__ ws)
{
  const int total = 74240 + 256 + 4608 + 12288 + 4096 + 4096 + 45312 + 65536 + 512;
  for (int idx = blockIdx.x * 256 + threadIdx.x; idx < total; idx += gridDim.x * 256) {
    int i = idx;
    if (i < 74240) {                       // W_P [290][256]
      int j = i >> 8, n = i & 255; float v;
      if (n < 64)       v = self_w[n * 580 + j] + self_w[n * 580 + 290 + j];
      else if (n < 128) v = e0w[(n - 64) * 306 + 16 + j];
      else if (n < 192) v = e1w[(n - 128) * 314 + 24 + j];
      else              v = e2w[(n - 192) * 322 + 32 + j];
      ws[WP_OFF + i] = v; continue;
    }
    i -= 74240;
    if (i < 256) {                         // b_P
      float v;
      if (i < 64) v = self_b[i];
      else if (i < 128) v = e0b[i - 64];
      else if (i < 192) v = e1b[i - 128];
      else v = e2b[i - 192];
      ws[BP_OFF + i] = v; continue;
    }
    i -= 256;
    if (i < 4608) {                        // WF transposed, per type
      float v;
      if (i < 1024)      { int d = i >> 6, n = i & 63; v = e0w[n * 306 + d]; }
      else if (i < 2560) { int q = i - 1024, d = q >> 6, n = q & 63; v = e1w[n * 314 + d]; }
      else               { int q = i - 2560, d = q >> 6, n = q & 63; v = e2w[n * 322 + d]; }
      ws[WF_OFF + i] = v; continue;
    }
    i -= 4608;
    if (i < 12288) {                       // WQKV [g][d][n]
      int g = i >> 12, q = i & 4095, d = q >> 6, n = q & 63;
      ws[WQKV_OFF + i] = ipw[(g * 64 + n) * 64 + d]; continue;
    }
    i -= 12288;
    if (i < 4096) { int d = i >> 6, n = i & 63; ws[WO_OFF + i]  = opw[n * 64 + d]; continue; }
    i -= 4096;
    if (i < 4096) { int d = i >> 6, n = i & 63; ws[WSA_OFF + i] = saw[n * 64 + d]; continue; }
    i -= 4096;
    if (i < 45312) { int k = i >> 7, n = i & 127; ws[PW_OFF + i] = plw[n * 354 + k]; continue; }
    i -= 45312;
    if (i < 65536) { int k = i >> 9, n = i & 511; ws[WIH_OFF + i] = wih[n * 128 + k]; continue; }
    i -= 65536;
    ws[BG_OFF + i] = bih[i] + bhh[i];
  }
}

// ---------------- conv + x_self assembly ----------------
__global__ __launch_bounds__(256) void k_assemble(
    const float* __restrict__ xa, const float* __restrict__ xl, const float* __restrict__ xs,
    const float* __restrict__ lw, const float* __restrict__ lb, float* __restrict__ X)
{
  const int total = 4096 * 290;
  for (int idx = blockIdx.x * 256 + threadIdx.x; idx < total; idx += gridDim.x * 256) {
    int m = idx / 290, j = idx - m * 290;
    float v;
    if (j < 16) v = xa[m * 16 + j];
    else if (j < 286) {
      int jj = j - 16; int c = jj / 30; int p = jj - c * 30;
      const float* xr = xl + m * 32 + p;
      v = lw[c * 3] * xr[0] + lw[c * 3 + 1] * xr[1] + lw[c * 3 + 2] * xr[2] + lb[c];
      v = fmaxf(v, 0.f);
    } else v = xs[m * 4 + (j - 286)];
    X[idx] = v;
  }
}

// ---------------- generic 64x64-tile fp32 GEMM: C = A(MxK) @ B(KxN) + bias ----------------
__global__ __launch_bounds__(256) void k_gemm64(
    const float* __restrict__ A, const float* __restrict__ Bm, const float* __restrict__ bias,
    float* __restrict__ C, int N, int K, int reluN)
{
  __shared__ float As[64][33];
  __shared__ float Bs[32][65];
  int m0 = blockIdx.x * 64, n0 = blockIdx.y * 64;
  int tid = threadIdx.x, tx = tid & 15, ty = tid >> 4;
  float acc[4][4] = {};
  for (int k0 = 0; k0 < K; k0 += 32) {
    #pragma unroll
    for (int l = 0; l < 8; ++l) {
      int e = tid + l * 256, r = e >> 5, cc = e & 31;
      int kk = k0 + cc;
      As[r][cc] = (kk < K) ? A[(size_t)(m0 + r) * K + kk] : 0.f;
    }
    #pragma unroll
    for (int l = 0; l < 8; ++l) {
      int e = tid + l * 256, r = e >> 6, cc = e & 63;
      int kk = k0 + r;
      Bs[r][cc] = (kk < K) ? Bm[(size_t)kk * N + n0 + cc] : 0.f;
    }
    __syncthreads();
    #pragma unroll
    for (int kk = 0; kk < 32; ++kk) {
      float a[4], b[4];
      #pragma unroll
      for (int i = 0; i < 4; ++i) a[i] = As[ty * 4 + i][kk];
      #pragma unroll
      for (int j = 0; j < 4; ++j) b[j] = Bs[kk][tx * 4 + j];
      #pragma unroll
      for (int i = 0; i < 4; ++i)
        #pragma unroll
        for (int j = 0; j < 4; ++j) acc[i][j] += a[i] * b[j];
    }
    __syncthreads();
  }
  #pragma unroll
  for (int i = 0; i < 4; ++i) {
    int row = m0 + ty * 4 + i;
    #pragma unroll
    for (int j = 0; j < 4; ++j) {
      int col = n0 + tx * 4 + j;
      float v = acc[i][j] + bias[col];
      if (col < reluN) v = fmaxf(v, 0.f);
      C[(size_t)row * N + col] = v;
    }
  }
}

// ---------------- pool GEMM with concat A = [X(290) | Y(64)] ----------------
__global__ __launch_bounds__(256) void k_gemm_pool(
    const float* __restrict__ X, const float* __restrict__ Yp,
    const float* __restrict__ Bm, const float* __restrict__ bias, float* __restrict__ C)
{
  __shared__ float As[64][33];
  __shared__ float Bs[32][65];
  const int K = 354, N = 128;
  int m0 = blockIdx.x * 64, n0 = blockIdx.y * 64;
  int tid = threadIdx.x, tx = tid & 15, ty = tid >> 4;
  float acc[4][4] = {};
  for (int k0 = 0; k0 < K; k0 += 32) {
    #pragma unroll
    for (int l = 0; l < 8; ++l) {
      int e = tid + l * 256, r = e >> 5, cc = e & 31;
      int kk = k0 + cc;
      float v = 0.f;
      if (kk < 290)      v = X[(size_t)(m0 + r) * 290 + kk];
      else if (kk < 354) v = Yp[(size_t)(m0 + r) * 64 + kk - 290];
      As[r][cc] = v;
    }
    #pragma unroll
    for (int l = 0; l < 8; ++l) {
      int e = tid + l * 256, r = e >> 6, cc = e & 63;
      int kk = k0 + r;
      Bs[r][cc] = (kk < K) ? Bm[(size_t)kk * N + n0 + cc] : 0.f;
    }
    __syncthreads();
    #pragma unroll
    for (int kk = 0; kk < 32; ++kk) {
      float a[4], b[4];
      #pragma unroll
      for (int i = 0; i < 4; ++i) a[i] = As[ty * 4 + i][kk];
      #pragma unroll
      for (int j = 0; j < 4; ++j) b[j] = Bs[kk][tx * 4 + j];
      #pragma unroll
      for (int i = 0; i < 4; ++i)
        #pragma unroll
        for (int j = 0; j < 4; ++j) acc[i][j] += a[i] * b[j];
    }
    __syncthreads();
  }
  #pragma unroll
  for (int i = 0; i < 4; ++i) {
    int row = m0 + ty * 4 + i;
    #pragma unroll
    for (int j = 0; j < 4; ++j) {
      int col = n0 + tx * 4 + j;
      float v = fmaxf(acc[i][j] + bias[col], 0.f);
      C[(size_t)row * 128 + col] = v;
    }
  }
}

// ---------------- entity-row encoder helper ----------------
template <int DK>
static __device__ __forceinline__ void ent_encode(
    const float* __restrict__ fP, const float* __restrict__ WF,
    const float* __restrict__ xsP, float* __restrict__ zent, int m, int w, int l, int t)
{
  float wreg[DK];
  #pragma unroll
  for (int d = 0; d < DK; ++d) wreg[d] = WF[d * 64 + l];
  float xb = xsP[64 + t * 64 + l];
  #pragma unroll
  for (int i = 0; i < 4; ++i) {
    int er = w + 4 * i;
    const float* fr = fP + (size_t)(m * 16 + er) * DK;
    float acc = xb;
    #pragma unroll
    for (int d4 = 0; d4 < DK / 4; ++d4) {
      float4 f4 = reinterpret_cast<const float4*>(fr)[d4];
      acc += f4.x * wreg[4 * d4] + f4.y * wreg[4 * d4 + 1] + f4.z * wreg[4 * d4 + 2] + f4.w * wreg[4 * d4 + 3];
    }
    zent[(1 + t * 16 + er) * 64 + l] = fmaxf(acc, 0.f);
  }
}

// ---------------- fused per-sample entity + attention + pool-reduce ----------------
__global__ __launch_bounds__(256) void k_attn(
    const float* __restrict__ Pmat,
    const float* __restrict__ f0, const float* __restrict__ f1, const float* __restrict__ f2,
    const float* __restrict__ mk0, const float* __restrict__ mk1, const float* __restrict__ mk2,
    const float* __restrict__ WF, const float* __restrict__ WQKV,
    const float* __restrict__ WO, const float* __restrict__ WSA,
    const float* __restrict__ ipb, const float* __restrict__ opb, const float* __restrict__ sab_,
    float* __restrict__ Y)
{
  __shared__ float zent[49 * 64];
  __shared__ float kb[49 * 64];
  __shared__ float vb[49 * 64];
  __shared__ float qb[49 * 65];     // padded: conflict-free per-row reads in C3
  __shared__ float sabuf[49 * 68];  // padded to mult-of-4 for aligned float4 reads in C4
  __shared__ float xsP[256];
  __shared__ float mv[49];
  int m = blockIdx.x;
  int tid = threadIdx.x, w = tid >> 6, l = tid & 63;

  // --- C0: load P row, mask vector, z_self row ---
  {
    float pv = Pmat[(size_t)m * 256 + tid];
    xsP[tid] = pv;
    if (tid < 64) zent[tid] = pv;  // row 0 = z_self (already biased+relu'd)
    if (tid == 0) mv[0] = 1.f;
    else if (tid < 17) mv[tid] = mk0[m * 16 + tid - 1];
    else if (tid < 33) mv[tid] = mk1[m * 16 + tid - 17];
    else if (tid < 49) mv[tid] = mk2[m * 16 + tid - 33];
  }
  __syncthreads();

  // --- C1: entity rows 1..48 ---
  ent_encode<16>(f0, WF + 0,    xsP, zent, m, w, l, 0);
  ent_encode<24>(f1, WF + 1024, xsP, zent, m, w, l, 1);
  ent_encode<32>(f2, WF + 2560, xsP, zent, m, w, l, 2);
  __syncthreads();

  // --- C2: q, k, v = z_ent @ W + b (weight column per lane, rows strided by wave) ---
  for (int g = 0; g < 3; ++g) {
    float* ob = (g == 0) ? qb : (g == 1) ? kb : vb;
    int ost = (g == 0) ? 65 : 64;
    float wreg[64];
    #pragma unroll
    for (int d = 0; d < 64; ++d) wreg[d] = WQKV[g * 4096 + d * 64 + l];
    float bs = ipb[g * 64 + l];
    for (int e = w; e < 49; e += 4) {
      const float4* z4 = reinterpret_cast<const float4*>(&zent[e * 64]);
      float acc = bs;
      #pragma unroll
      for (int d4 = 0; d4 < 16; ++d4) {
        float4 f4 = z4[d4];
        acc += f4.x * wreg[4 * d4] + f4.y * wreg[4 * d4 + 1] + f4.z * wreg[4 * d4 + 2] + f4.w * wreg[4 * d4 + 3];
      }
      ob[e * ost + l] = acc;
    }
  }
  __syncthreads();

  // --- C3: masked multi-head attention; wave = head, lane = query row ---
  if (l < 49) {
    int h = w;
    float qr[16];
    #pragma unroll
    for (int i = 0; i < 16; ++i) qr[i] = qb[l * 65 + h * 16 + i];
    float s[49];
    float mx = -1e30f;
    #pragma unroll
    for (int j = 0; j < 49; ++j) {
      const float4* k4 = reinterpret_cast<const float4*>(&kb[j * 64 + h * 16]);
      float sc = 0.f;
      #pragma unroll
      for (int i4 = 0; i4 < 4; ++i4) {
        float4 f4 = k4[i4];
        sc += f4.x * qr[4 * i4] + f4.y * qr[4 * i4 + 1] + f4.z * qr[4 * i4 + 2] + f4.w * qr[4 * i4 + 3];
      }
      sc *= 0.25f;
      s[j] = sc;
      if (mv[j] != 0.f) mx = fmaxf(mx, sc);
    }
    float sum = 0.f;
    float4 acc4[4] = {};
    #pragma unroll
    for (int j = 0; j < 49; ++j) {
      float p = (mv[j] != 0.f) ? __expf(s[j] - mx) : 0.f;
      sum += p;
      const float4* v4 = reinterpret_cast<const float4*>(&vb[j * 64 + h * 16]);
      #pragma unroll
      for (int i4 = 0; i4 < 4; ++i4) {
        float4 f4 = v4[i4];
        acc4[i4].x += p * f4.x; acc4[i4].y += p * f4.y; acc4[i4].z += p * f4.z; acc4[i4].w += p * f4.w;
      }
    }
    float inv = 1.f / sum;
    #pragma unroll
    for (int i4 = 0; i4 < 4; ++i4) {
      sabuf[l * 68 + h * 16 + 4 * i4 + 0] = acc4[i4].x * inv;
      sabuf[l * 68 + h * 16 + 4 * i4 + 1] = acc4[i4].y * inv;
      sabuf[l * 68 + h * 16 + 4 * i4 + 2] = acc4[i4].z * inv;
      sabuf[l * 68 + h * 16 + 4 * i4 + 3] = acc4[i4].w * inv;
    }
  }
  __syncthreads();

  // --- C4: out_proj (o into kb, no relu) ---
  {
    float wreg[64];
    #pragma unroll
    for (int d = 0; d < 64; ++d) wreg[d] = WO[d * 64 + l];
    float bs = opb[l];
    for (int e = w; e < 49; e += 4) {
      const float4* s4 = reinterpret_cast<const float4*>(&sabuf[e * 68]);
      float acc = bs;
      #pragma unroll
      for (int d4 = 0; d4 < 16; ++d4) {
        float4 f4 = s4[d4];
        acc += f4.x * wreg[4 * d4] + f4.y * wreg[4 * d4 + 1] + f4.z * wreg[4 * d4 + 2] + f4.w * wreg[4 * d4 + 3];
      }
      kb[e * 64 + l] = acc;
    }
  }
  __syncthreads();

  // --- C5: sa_w + relu + residual + masked mean ---
  {
    float wreg[64];
    #pragma unroll
    for (int d = 0; d < 64; ++d) wreg[d] = WSA[d * 64 + l];
    float bs = sab_[l];
    float pacc = 0.f;
    for (int e = w; e < 49; e += 4) {
      const float4* o4 = reinterpret_cast<const float4*>(&kb[e * 64]);
      float acc = bs;
      #pragma unroll
      for (int d4 = 0; d4 < 16; ++d4) {
        float4 f4 = o4[d4];
        acc += f4.x * wreg[4 * d4] + f4.y * wreg[4 * d4 + 1] + f4.z * wreg[4 * d4 + 2] + f4.w * wreg[4 * d4 + 3];
      }
      float r = zent[e * 64 + l] + fmaxf(acc, 0.f);
      pacc += r * mv[e];
    }
    float* part = qb;  // qb dead after C3 — reuse as 4x64 partial buffer
    part[w * 64 + l] = pacc;
  }
  __syncthreads();
  if (tid < 64) {
    const float* part = qb;
    float zp = (part[tid] + part[64 + tid] + part[128 + tid] + part[192 + tid]) * (1.f / 49.f);
    Y[(size_t)m * 64 + tid] = zp;
  }
}

// ---------------- LSTM scan + value head: block = one (b,a) sequence ----------------
__global__ __launch_bounds__(512) void k_lstm(
    const float* __restrict__ Gx, const float* __restrict__ whh,
    const float* __restrict__ done, const float* __restrict__ h0, const float* __restrict__ c0,
    const float* __restrict__ hw, const float* __restrict__ hb, float* __restrict__ out)
{
  __shared__ float h[128], c[128], gl[512], red[2];
  int s = blockIdx.x, b = s >> 3;
  int g = threadIdx.x;
  float wreg[128];
  {
    const float4* w4 = reinterpret_cast<const float4*>(whh + (size_t)g * 128);
    #pragma unroll
    for (int j4 = 0; j4 < 32; ++j4) {
      float4 f4 = w4[j4];
      wreg[4 * j4] = f4.x; wreg[4 * j4 + 1] = f4.y; wreg[4 * j4 + 2] = f4.z; wreg[4 * j4 + 3] = f4.w;
    }
  }
  if (g < 128) { h[g] = h0[s * 128 + g]; c[g] = c0[s * 128 + g]; }
  __syncthreads();
  for (int t = 0; t < 32; ++t) {
    float keep = 1.f - done[t * 16 + b];
    float acc = 0.f;
    const float4* h4 = reinterpret_cast<const float4*>(h);
    #pragma unroll
    for (int j4 = 0; j4 < 32; ++j4) {
      float4 f4 = h4[j4];
      acc += f4.x * wreg[4 * j4] + f4.y * wreg[4 * j4 + 1] + f4.z * wreg[4 * j4 + 2] + f4.w * wreg[4 * j4 + 3];
    }
    gl[g] = Gx[(size_t)(t * 128 + s) * 512 + g] + keep * acc;
    __syncthreads();
    if (g < 128) {
      float iv = sigf(gl[g]);
      float fv = sigf(gl[128 + g]);
      float gg = tanhf(gl[256 + g]);
      float ov = sigf(gl[384 + g]);
      float cn = fv * (c[g] * keep) + iv * gg;
      float hn = ov * tanhf(cn);
      c[g] = cn; h[g] = hn;
      float pv = hn * hw[g];
      #pragma unroll
      for (int off = 32; off > 0; off >>= 1) pv += __shfl_down(pv, off, 64);
      if ((g & 63) == 0) red[g >> 6] = pv;
    }
    __syncthreads();
    if (g == 0) out[t * 128 + s] = red[0] + red[1] + hb[0];
  }
}

// ---------------- launch ----------------
extern "C" void kernel_launch(void* const* d_in, const int* in_sizes, int n_in,
                              void* d_out, int out_size, void* d_ws, size_t ws_size,
                              hipStream_t stream) {
  const float* x_agent = (const float*)d_in[0];
  const float* x_lidar = (const float*)d_in[1];
  const float* x_safe  = (const float*)d_in[2];
  const float* ef0 = (const float*)d_in[3];
  const float* em0 = (const float*)d_in[4];
  const float* ef1 = (const float*)d_in[5];
  const float* em1 = (const float*)d_in[6];
  const float* ef2 = (const float*)d_in[7];
  const float* em2 = (const float*)d_in[8];
  const float* done = (const float*)d_in[9];
  const float* h0 = (const float*)d_in[10];
  const float* c0 = (const float*)d_in[11];
  const float* lw = (const float*)d_in[12];
  const float* lb = (const float*)d_in[13];
  const float* self_w = (const float*)d_in[14];
  const float* self_b = (const float*)d_in[15];
  const float* e0w = (const float*)d_in[16];
  const float* e0b = (const float*)d_in[17];
  const float* e1w = (const float*)d_in[18];
  const float* e1b = (const float*)d_in[19];
  const float* e2w = (const float*)d_in[20];
  const float* e2b = (const float*)d_in[21];
  const float* ipw = (const float*)d_in[22];
  const float* ipb = (const float*)d_in[23];
  const float* opw = (const float*)d_in[24];
  const float* opb = (const float*)d_in[25];
  const float* saw = (const float*)d_in[26];
  const float* sab = (const float*)d_in[27];
  const float* plw = (const float*)d_in[28];
  const float* plb = (const float*)d_in[29];
  const float* wih = (const float*)d_in[30];
  const float* whh = (const float*)d_in[31];
  const float* bih = (const float*)d_in[32];
  const float* bhh = (const float*)d_in[33];
  const float* hw  = (const float*)d_in[34];
  const float* hb  = (const float*)d_in[35];
  float* ws  = (float*)d_ws;
  float* out = (float*)d_out;

  k_prep<<<256, 256, 0, stream>>>(self_w, self_b, e0w, e0b, e1w, e1b, e2w, e2b,
                                  ipw, opw, saw, plw, wih, bih, bhh, ws);
  k_assemble<<<2048, 256, 0, stream>>>(x_agent, x_lidar, x_safe, lw, lb, ws + X_OFF);
  {
    dim3 g(64, 4);
    k_gemm64<<<g, 256, 0, stream>>>(ws + X_OFF, ws + WP_OFF, ws + BP_OFF, ws + P_OFF, 256, 290, 64);
  }
  k_attn<<<4096, 256, 0, stream>>>(ws + P_OFF, ef0, ef1, ef2, em0, em1, em2,
                                   ws + WF_OFF, ws + WQKV_OFF, ws + WO_OFF, ws + WSA_OFF,
                                   ipb, opb, sab, ws + Y_OFF);
  {
    dim3 g(64, 2);
    k_gemm_pool<<<g, 256, 0, stream>>>(ws + X_OFF, ws + Y_OFF, ws + PW_OFF, plb, ws + Z_OFF);
  }
  {
    dim3 g(64, 8);
    k_gemm64<<<g, 256, 0, stream>>>(ws + Z_OFF, ws + WIH_OFF, ws + BG_OFF, ws + GX_OFF, 512, 128, 0);
  }
  k_lstm<<<128, 512, 0, stream>>>(ws + GX_OFF, whh, done, h0, c0, hw, hb, out);
}

// Round 4
// 448.875 us; speedup vs baseline: 1.4205x; 1.4205x over previous
//
#include <hip/hip_runtime.h>
#include <math.h>

// ---------------- workspace layout (float offsets) ----------------
constexpr size_t X_OFF    = 0;               // 4096*290
constexpr size_t WP_OFF   = 1187840;         // 290*256
constexpr size_t BP_OFF   = 1262080;         // 256
constexpr size_t P_OFF    = 1262336;         // 4096*256
constexpr size_t WF_OFF   = 2310912;         // 72*64 (t0@0,t1@1024,t2@2560)
constexpr size_t WQKV_OFF = 2315520;         // frag bf16: 12288 ushorts (fits in old 12288-float slot)
constexpr size_t WO_OFF   = 2327808;         // frag bf16: 4096 ushorts
constexpr size_t WSA_OFF  = 2331904;         // frag bf16: 4096 ushorts
constexpr size_t Y_OFF    = 2336000;         // 4096*64   (z_pool)
constexpr size_t PW_OFF   = 2598144;         // 354*128
constexpr size_t Z_OFF    = 2643456;         // 4096*128
constexpr size_t WIH_OFF  = 3167744;         // 128*512
constexpr size_t BG_OFF   = 3233280;         // 512
constexpr size_t GX_OFF   = 3233792;         // 4096*512

typedef float f32x4 __attribute__((ext_vector_type(4)));
typedef __bf16 bf16x8v __attribute__((ext_vector_type(8)));
typedef unsigned short us8 __attribute__((ext_vector_type(8)));
union b8u { us8 u; bf16x8v b; };

static __device__ __forceinline__ float sigf(float x) { return 1.0f / (1.0f + __expf(-x)); }

// f32 -> bf16 bits, round-to-nearest-even
static __device__ __forceinline__ unsigned short f2b(float x) {
  unsigned int u = __float_as_uint(x);
  unsigned int r = (u + 0x7FFFu + ((u >> 16) & 1u)) >> 16;
  return (unsigned short)r;
}
static __device__ __forceinline__ float b2f(unsigned short s) {
  return __uint_as_float(((unsigned int)s) << 16);
}
static __device__ __forceinline__ bf16x8v ld_bf8(const unsigned short* p) {
  b8u c; c.u = *(const us8*)p; return c.b;
}

// ---------------- prep: fold & transpose weights (+ bf16 MFMA B-fragments) ----------------
// MFMA 16x16x32 bf16 fragment convention used throughout:
//   A: lane l holds A[row = l&15][k = 8*(l>>4)+j], j=0..7  (8 contiguous bf16)
//   B: lane l holds B[k = 8*(l>>4)+j][col = l&15]
//   D: lane l holds D[row = 4*(l>>4)+i][col = l&15]   (verified layout, m89)
__global__ __launch_bounds__(256) void k_prep(
    const float* __restrict__ self_w, const float* __restrict__ self_b,
    const float* __restrict__ e0w, const float* __restrict__ e0b,
    const float* __restrict__ e1w, const float* __restrict__ e1b,
    const float* __restrict__ e2w, const float* __restrict__ e2b,
    const float* __restrict__ ipw, const float* __restrict__ opw,
    const float* __restrict__ saw, const float* __restrict__ plw,
    const float* __restrict__ wih, const float* __restrict__ bih,
    const float* __restrict__ bhh, float* __restrict__ ws)
{
  unsigned short* QKVF = (unsigned short*)(ws + WQKV_OFF);
  unsigned short* WOF  = (unsigned short*)(ws + WO_OFF);
  unsigned short* WSAF = (unsigned short*)(ws + WSA_OFF);
  const int NF = 74240 + 256 + 4608 + 45312 + 65536 + 512;   // float items
  const int total = NF + 12288 + 4096 + 4096;                // + bf16 frag items
  for (int idx = blockIdx.x * 256 + threadIdx.x; idx < total; idx += gridDim.x * 256) {
    int i = idx;
    if (i < 74240) {                       // W_P [290][256]
      int j = i >> 8, n = i & 255; float v;
      if (n < 64)       v = self_w[n * 580 + j] + self_w[n * 580 + 290 + j];
      else if (n < 128) v = e0w[(n - 64) * 306 + 16 + j];
      else if (n < 192) v = e1w[(n - 128) * 314 + 24 + j];
      else              v = e2w[(n - 192) * 322 + 32 + j];
      ws[WP_OFF + i] = v; continue;
    }
    i -= 74240;
    if (i < 256) {                         // b_P
      float v;
      if (i < 64) v = self_b[i];
      else if (i < 128) v = e0b[i - 64];
      else if (i < 192) v = e1b[i - 128];
      else v = e2b[i - 192];
      ws[BP_OFF + i] = v; continue;
    }
    i -= 256;
    if (i < 4608) {                        // WF transposed [d][64], per type
      float v;
      if (i < 1024)      { int d = i >> 6, n = i & 63; v = e0w[n * 306 + d]; }
      else if (i < 2560) { int q = i - 1024, d = q >> 6, n = q & 63; v = e1w[n * 314 + d]; }
      else               { int q = i - 2560, d = q >> 6, n = q & 63; v = e2w[n * 322 + d]; }
      ws[WF_OFF + i] = v; continue;
    }
    i -= 4608;
    if (i < 45312) { int k = i >> 7, n = i & 127; ws[PW_OFF + i] = plw[n * 354 + k]; continue; }
    i -= 45312;
    if (i < 65536) { int k = i >> 9, n = i & 511; ws[WIH_OFF + i] = wih[n * 128 + k]; continue; }
    i -= 65536;
    if (i < 512) { ws[BG_OFF + i] = bih[i] + bhh[i]; continue; }
    i -= 512;
    // bf16 B-fragments: item f = ((ct*2+kt)*64 + l)*8 + j
    if (i < 12288) {
      int ct = i >> 10, kt = (i >> 9) & 1, ll = (i >> 3) & 63, j = i & 7;
      int d = kt * 32 + 8 * (ll >> 4) + j;
      int n = ct * 16 + (ll & 15);
      QKVF[i] = f2b(ipw[n * 64 + d]); continue;
    }
    i -= 12288;
    if (i < 4096) {
      int ct = i >> 10, kt = (i >> 9) & 1, ll = (i >> 3) & 63, j = i & 7;
      int d = kt * 32 + 8 * (ll >> 4) + j;
      int n = ct * 16 + (ll & 15);
      WOF[i] = f2b(opw[n * 64 + d]); continue;
    }
    i -= 4096;
    {
      int ct = i >> 10, kt = (i >> 9) & 1, ll = (i >> 3) & 63, j = i & 7;
      int d = kt * 32 + 8 * (ll >> 4) + j;
      int n = ct * 16 + (ll & 15);
      WSAF[i] = f2b(saw[n * 64 + d]);
    }
  }
}

// ---------------- conv + x_self assembly ----------------
__global__ __launch_bounds__(256) void k_assemble(
    const float* __restrict__ xa, const float* __restrict__ xl, const float* __restrict__ xs,
    const float* __restrict__ lw, const float* __restrict__ lb, float* __restrict__ X)
{
  const int total = 4096 * 290;
  for (int idx = blockIdx.x * 256 + threadIdx.x; idx < total; idx += gridDim.x * 256) {
    int m = idx / 290, j = idx - m * 290;
    float v;
    if (j < 16) v = xa[m * 16 + j];
    else if (j < 286) {
      int jj = j - 16; int c = jj / 30; int p = jj - c * 30;
      const float* xr = xl + m * 32 + p;
      v = lw[c * 3] * xr[0] + lw[c * 3 + 1] * xr[1] + lw[c * 3 + 2] * xr[2] + lb[c];
      v = fmaxf(v, 0.f);
    } else v = xs[m * 4 + (j - 286)];
    X[idx] = v;
  }
}

// ---------------- generic 64x64-tile fp32 GEMM: C = A(MxK) @ B(KxN) + bias ----------------
__global__ __launch_bounds__(256) void k_gemm64(
    const float* __restrict__ A, const float* __restrict__ Bm, const float* __restrict__ bias,
    float* __restrict__ C, int N, int K, int reluN)
{
  __shared__ float As[64][33];
  __shared__ float Bs[32][65];
  int m0 = blockIdx.x * 64, n0 = blockIdx.y * 64;
  int tid = threadIdx.x, tx = tid & 15, ty = tid >> 4;
  float acc[4][4] = {};
  for (int k0 = 0; k0 < K; k0 += 32) {
    #pragma unroll
    for (int l = 0; l < 8; ++l) {
      int e = tid + l * 256, r = e >> 5, cc = e & 31;
      int kk = k0 + cc;
      As[r][cc] = (kk < K) ? A[(size_t)(m0 + r) * K + kk] : 0.f;
    }
    #pragma unroll
    for (int l = 0; l < 8; ++l) {
      int e = tid + l * 256, r = e >> 6, cc = e & 63;
      int kk = k0 + r;
      Bs[r][cc] = (kk < K) ? Bm[(size_t)kk * N + n0 + cc] : 0.f;
    }
    __syncthreads();
    #pragma unroll
    for (int kk = 0; kk < 32; ++kk) {
      float a[4], b[4];
      #pragma unroll
      for (int i = 0; i < 4; ++i) a[i] = As[ty * 4 + i][kk];
      #pragma unroll
      for (int j = 0; j < 4; ++j) b[j] = Bs[kk][tx * 4 + j];
      #pragma unroll
      for (int i = 0; i < 4; ++i)
        #pragma unroll
        for (int j = 0; j < 4; ++j) acc[i][j] += a[i] * b[j];
    }
    __syncthreads();
  }
  #pragma unroll
  for (int i = 0; i < 4; ++i) {
    int row = m0 + ty * 4 + i;
    #pragma unroll
    for (int j = 0; j < 4; ++j) {
      int col = n0 + tx * 4 + j;
      float v = acc[i][j] + bias[col];
      if (col < reluN) v = fmaxf(v, 0.f);
      C[(size_t)row * N + col] = v;
    }
  }
}

// ---------------- pool GEMM with concat A = [X(290) | Y(64)] ----------------
__global__ __launch_bounds__(256) void k_gemm_pool(
    const float* __restrict__ X, const float* __restrict__ Yp,
    const float* __restrict__ Bm, const float* __restrict__ bias, float* __restrict__ C)
{
  __shared__ float As[64][33];
  __shared__ float Bs[32][65];
  const int K = 354, N = 128;
  int m0 = blockIdx.x * 64, n0 = blockIdx.y * 64;
  int tid = threadIdx.x, tx = tid & 15, ty = tid >> 4;
  float acc[4][4] = {};
  for (int k0 = 0; k0 < K; k0 += 32) {
    #pragma unroll
    for (int l = 0; l < 8; ++l) {
      int e = tid + l * 256, r = e >> 5, cc = e & 31;
      int kk = k0 + cc;
      float v = 0.f;
      if (kk < 290)      v = X[(size_t)(m0 + r) * 290 + kk];
      else if (kk < 354) v = Yp[(size_t)(m0 + r) * 64 + kk - 290];
      As[r][cc] = v;
    }
    #pragma unroll
    for (int l = 0; l < 8; ++l) {
      int e = tid + l * 256, r = e >> 6, cc = e & 63;
      int kk = k0 + r;
      Bs[r][cc] = (kk < K) ? Bm[(size_t)kk * N + n0 + cc] : 0.f;
    }
    __syncthreads();
    #pragma unroll
    for (int kk = 0; kk < 32; ++kk) {
      float a[4], b[4];
      #pragma unroll
      for (int i = 0; i < 4; ++i) a[i] = As[ty * 4 + i][kk];
      #pragma unroll
      for (int j = 0; j < 4; ++j) b[j] = Bs[kk][tx * 4 + j];
      #pragma unroll
      for (int i = 0; i < 4; ++i)
        #pragma unroll
        for (int j = 0; j < 4; ++j) acc[i][j] += a[i] * b[j];
    }
    __syncthreads();
  }
  #pragma unroll
  for (int i = 0; i < 4; ++i) {
    int row = m0 + ty * 4 + i;
    #pragma unroll
    for (int j = 0; j < 4; ++j) {
      int col = n0 + tx * 4 + j;
      float v = fmaxf(acc[i][j] + bias[col], 0.f);
      C[(size_t)row * 128 + col] = v;
    }
  }
}

// ---------------- entity-row encoder: writes bf16 rows into zh (stride 72) ----------------
template <int DK>
static __device__ __forceinline__ void ent_encode(
    const float* __restrict__ fP, const float* __restrict__ WF,
    const float* __restrict__ xsP, unsigned short* __restrict__ zh, int m, int w, int l, int t)
{
  float wreg[DK];
  #pragma unroll
  for (int d = 0; d < DK; ++d) wreg[d] = WF[d * 64 + l];
  float xb = xsP[64 + t * 64 + l];
  #pragma unroll
  for (int i = 0; i < 4; ++i) {
    int er = w + 4 * i;
    const float* fr = fP + (size_t)(m * 16 + er) * DK;
    float acc = xb;
    #pragma unroll
    for (int d4 = 0; d4 < DK / 4; ++d4) {
      float4 f4 = reinterpret_cast<const float4*>(fr)[d4];
      acc += f4.x * wreg[4 * d4] + f4.y * wreg[4 * d4 + 1] + f4.z * wreg[4 * d4 + 2] + f4.w * wreg[4 * d4 + 3];
    }
    zh[(1 + t * 16 + er) * 72 + l] = f2b(fmaxf(acc, 0.f));
  }
}

// ---------------- fused per-sample entity + attention + pool-reduce (MFMA) ----------------
__global__ __launch_bounds__(256, 3) void k_attn(
    const float* __restrict__ Pmat,
    const float* __restrict__ f0, const float* __restrict__ f1, const float* __restrict__ f2,
    const float* __restrict__ mk0, const float* __restrict__ mk1, const float* __restrict__ mk2,
    const float* __restrict__ WF,
    const unsigned short* __restrict__ QKVF,
    const unsigned short* __restrict__ WOF,
    const unsigned short* __restrict__ WSAF,
    const float* __restrict__ ipb, const float* __restrict__ opb, const float* __restrict__ sab_,
    float* __restrict__ Y)
{
  __shared__ unsigned short zh[64 * 72];   // z_ent bf16, stride-72 pad (2-way-free MFMA A reads)
  __shared__ unsigned short qh[49 * 72];   // q bf16
  __shared__ float kf[49 * 64];            // k fp32 (o_h bf16 overlays after C3)
  __shared__ float vf[49 * 64];            // v fp32
  __shared__ unsigned short sah[64 * 72];  // attention out bf16
  __shared__ float xsP[256];
  __shared__ float mv[52];
  unsigned short* oh = (unsigned short*)kf;
  int m = blockIdx.x;
  int tid = threadIdx.x, w = tid >> 6, l = tid & 63;
  int lr = l & 15, lg = l >> 4;

  // --- C0: load P row, mask vector, z_self row ---
  {
    float pv = Pmat[(size_t)m * 256 + tid];
    xsP[tid] = pv;
    if (tid < 64) zh[tid] = f2b(pv);  // row 0 = z_self
    if (tid == 0) mv[0] = 1.f;
    else if (tid < 17) mv[tid] = mk0[m * 16 + tid - 1];
    else if (tid < 33) mv[tid] = mk1[m * 16 + tid - 17];
    else if (tid < 49) mv[tid] = mk2[m * 16 + tid - 33];
  }
  __syncthreads();

  // --- C1: entity rows 1..48 (fp32 VALU, bf16 store) ---
  ent_encode<16>(f0, WF + 0,    xsP, zh, m, w, l, 0);
  ent_encode<24>(f1, WF + 1024, xsP, zh, m, w, l, 1);
  ent_encode<32>(f2, WF + 2560, xsP, zh, m, w, l, 2);
  __syncthreads();

  // --- C2: q,k,v = z @ Wqkv + b via MFMA; wave w owns col-tiles {w, w+4, w+8} ---
  {
    bf16x8v za[4][2];
    #pragma unroll
    for (int rt = 0; rt < 4; ++rt)
      #pragma unroll
      for (int kt = 0; kt < 2; ++kt)
        za[rt][kt] = ld_bf8(&zh[(rt * 16 + lr) * 72 + kt * 32 + 8 * lg]);
    #pragma unroll
    for (int cc = 0; cc < 3; ++cc) {
      int ct = w + 4 * cc;
      bf16x8v b0 = ld_bf8(&QKVF[((ct * 2 + 0) * 64 + l) * 8]);
      bf16x8v b1 = ld_bf8(&QKVF[((ct * 2 + 1) * 64 + l) * 8]);
      int n = ct * 16 + lr;
      float bias = ipb[n];
      #pragma unroll
      for (int rt = 0; rt < 4; ++rt) {
        f32x4 acc = {0.f, 0.f, 0.f, 0.f};
        acc = __builtin_amdgcn_mfma_f32_16x16x32_bf16(za[rt][0], b0, acc, 0, 0, 0);
        acc = __builtin_amdgcn_mfma_f32_16x16x32_bf16(za[rt][1], b1, acc, 0, 0, 0);
        #pragma unroll
        for (int i = 0; i < 4; ++i) {
          int r = rt * 16 + lg * 4 + i;
          if (r < 49) {
            float val = acc[i] + bias;
            if (cc == 0)      qh[r * 72 + n] = f2b(val);
            else if (cc == 1) kf[r * 64 + (n - 64)] = val;
            else              vf[r * 64 + (n - 128)] = val;
          }
        }
      }
    }
  }
  __syncthreads();

  // --- C3: masked multi-head attention (fp32); wave = head, lane = query row ---
  if (l < 49) {
    int h = w;
    float qr[16];
    {
      us8 ua = *(const us8*)&qh[l * 72 + h * 16];
      us8 ub = *(const us8*)&qh[l * 72 + h * 16 + 8];
      #pragma unroll
      for (int i = 0; i < 8; ++i) { qr[i] = b2f(ua[i]); qr[8 + i] = b2f(ub[i]); }
    }
    float s[49];
    float mx = -1e30f;
    #pragma unroll
    for (int j = 0; j < 49; ++j) {
      const float4* k4 = reinterpret_cast<const float4*>(&kf[j * 64 + h * 16]);
      float sc = 0.f;
      #pragma unroll
      for (int i4 = 0; i4 < 4; ++i4) {
        float4 f4 = k4[i4];
        sc += f4.x * qr[4 * i4] + f4.y * qr[4 * i4 + 1] + f4.z * qr[4 * i4 + 2] + f4.w * qr[4 * i4 + 3];
      }
      sc *= 0.25f;
      s[j] = sc;
      if (mv[j] != 0.f) mx = fmaxf(mx, sc);
    }
    float sum = 0.f;
    float4 acc4[4] = {};
    #pragma unroll
    for (int j = 0; j < 49; ++j) {
      float p = (mv[j] != 0.f) ? __expf(s[j] - mx) : 0.f;
      sum += p;
      const float4* v4 = reinterpret_cast<const float4*>(&vf[j * 64 + h * 16]);
      #pragma unroll
      for (int i4 = 0; i4 < 4; ++i4) {
        float4 f4 = v4[i4];
        acc4[i4].x += p * f4.x; acc4[i4].y += p * f4.y; acc4[i4].z += p * f4.z; acc4[i4].w += p * f4.w;
      }
    }
    float inv = 1.f / sum;
    #pragma unroll
    for (int i4 = 0; i4 < 4; ++i4) {
      sah[l * 72 + h * 16 + 4 * i4 + 0] = f2b(acc4[i4].x * inv);
      sah[l * 72 + h * 16 + 4 * i4 + 1] = f2b(acc4[i4].y * inv);
      sah[l * 72 + h * 16 + 4 * i4 + 2] = f2b(acc4[i4].z * inv);
      sah[l * 72 + h * 16 + 4 * i4 + 3] = f2b(acc4[i4].w * inv);
    }
  }
  __syncthreads();

  // --- C4: o = sa @ Wo + b via MFMA (oh overlays kf) ---
  {
    int ct = w, n = ct * 16 + lr;
    bf16x8v b0 = ld_bf8(&WOF[((ct * 2 + 0) * 64 + l) * 8]);
    bf16x8v b1 = ld_bf8(&WOF[((ct * 2 + 1) * 64 + l) * 8]);
    float bias = opb[n];
    bf16x8v sa0[4][2];
    #pragma unroll
    for (int rt = 0; rt < 4; ++rt)
      #pragma unroll
      for (int kt = 0; kt < 2; ++kt)
        sa0[rt][kt] = ld_bf8(&sah[(rt * 16 + lr) * 72 + kt * 32 + 8 * lg]);
    __syncthreads();  // ensure all C3 reads of kf done before oh overlay write
    #pragma unroll
    for (int rt = 0; rt < 4; ++rt) {
      f32x4 acc = {0.f, 0.f, 0.f, 0.f};
      acc = __builtin_amdgcn_mfma_f32_16x16x32_bf16(sa0[rt][0], b0, acc, 0, 0, 0);
      acc = __builtin_amdgcn_mfma_f32_16x16x32_bf16(sa0[rt][1], b1, acc, 0, 0, 0);
      #pragma unroll
      for (int i = 0; i < 4; ++i) {
        int r = rt * 16 + lg * 4 + i;
        if (r < 49) oh[r * 72 + n] = f2b(acc[i] + bias);
      }
    }
  }
  __syncthreads();

  // --- C5: res = z + relu(o @ Wsa + b); masked mean over entities ---
  {
    int ct = w, n = ct * 16 + lr;
    bf16x8v b0 = ld_bf8(&WSAF[((ct * 2 + 0) * 64 + l) * 8]);
    bf16x8v b1 = ld_bf8(&WSAF[((ct * 2 + 1) * 64 + l) * 8]);
    float bias = sab_[n];
    float pacc = 0.f;
    #pragma unroll
    for (int rt = 0; rt < 4; ++rt) {
      bf16x8v a0 = ld_bf8(&oh[(rt * 16 + lr) * 72 + 8 * lg]);
      bf16x8v a1 = ld_bf8(&oh[(rt * 16 + lr) * 72 + 32 + 8 * lg]);
      f32x4 acc = {0.f, 0.f, 0.f, 0.f};
      acc = __builtin_amdgcn_mfma_f32_16x16x32_bf16(a0, b0, acc, 0, 0, 0);
      acc = __builtin_amdgcn_mfma_f32_16x16x32_bf16(a1, b1, acc, 0, 0, 0);
      #pragma unroll
      for (int i = 0; i < 4; ++i) {
        int r = rt * 16 + lg * 4 + i;
        if (r < 49) {
          float val = fmaxf(acc[i] + bias, 0.f);
          float z = b2f(zh[r * 72 + n]);
          pacc += (z + val) * mv[r];
        }
      }
    }
    pacc += __shfl_xor(pacc, 16, 64);
    pacc += __shfl_xor(pacc, 32, 64);
    if (lg == 0) Y[(size_t)m * 64 + n] = pacc * (1.0f / 49.0f);
  }
}

// ---------------- LSTM scan + value head: block = one (b,a) sequence ----------------
__global__ __launch_bounds__(512) void k_lstm(
    const float* __restrict__ Gx, const float* __restrict__ whh,
    const float* __restrict__ done, const float* __restrict__ h0, const float* __restrict__ c0,
    const float* __restrict__ hw, const float* __restrict__ hb, float* __restrict__ out)
{
  __shared__ float h[128], c[128], gl[512], red[2];
  int s = blockIdx.x, b = s >> 3;
  int g = threadIdx.x;
  float wreg[128];
  {
    const float4* w4 = reinterpret_cast<const float4*>(whh + (size_t)g * 128);
    #pragma unroll
    for (int j4 = 0; j4 < 32; ++j4) {
      float4 f4 = w4[j4];
      wreg[4 * j4] = f4.x; wreg[4 * j4 + 1] = f4.y; wreg[4 * j4 + 2] = f4.z; wreg[4 * j4 + 3] = f4.w;
    }
  }
  if (g < 128) { h[g] = h0[s * 128 + g]; c[g] = c0[s * 128 + g]; }
  __syncthreads();
  for (int t = 0; t < 32; ++t) {
    float keep = 1.f - done[t * 16 + b];
    float acc = 0.f;
    const float4* h4 = reinterpret_cast<const float4*>(h);
    #pragma unroll
    for (int j4 = 0; j4 < 32; ++j4) {
      float4 f4 = h4[j4];
      acc += f4.x * wreg[4 * j4] + f4.y * wreg[4 * j4 + 1] + f4.z * wreg[4 * j4 + 2] + f4.w * wreg[4 * j4 + 3];
    }
    gl[g] = Gx[(size_t)(t * 128 + s) * 512 + g] + keep * acc;
    __syncthreads();
    if (g < 128) {
      float iv = sigf(gl[g]);
      float fv = sigf(gl[128 + g]);
      float gg = tanhf(gl[256 + g]);
      float ov = sigf(gl[384 + g]);
      float cn = fv * (c[g] * keep) + iv * gg;
      float hn = ov * tanhf(cn);
      c[g] = cn; h[g] = hn;
      float pv = hn * hw[g];
      #pragma unroll
      for (int off = 32; off > 0; off >>= 1) pv += __shfl_down(pv, off, 64);
      if ((g & 63) == 0) red[g >> 6] = pv;
    }
    __syncthreads();
    if (g == 0) out[t * 128 + s] = red[0] + red[1] + hb[0];
  }
}

// ---------------- launch ----------------
extern "C" void kernel_launch(void* const* d_in, const int* in_sizes, int n_in,
                              void* d_out, int out_size, void* d_ws, size_t ws_size,
                              hipStream_t stream) {
  const float* x_agent = (const float*)d_in[0];
  const float* x_lidar = (const float*)d_in[1];
  const float* x_safe  = (const float*)d_in[2];
  const float* ef0 = (const float*)d_in[3];
  const float* em0 = (const float*)d_in[4];
  const float* ef1 = (const float*)d_in[5];
  const float* em1 = (const float*)d_in[6];
  const float* ef2 = (const float*)d_in[7];
  const float* em2 = (const float*)d_in[8];
  const float* done = (const float*)d_in[9];
  const float* h0 = (const float*)d_in[10];
  const float* c0 = (const float*)d_in[11];
  const float* lw = (const float*)d_in[12];
  const float* lb = (const float*)d_in[13];
  const float* self_w = (const float*)d_in[14];
  const float* self_b = (const float*)d_in[15];
  const float* e0w = (const float*)d_in[16];
  const float* e0b = (const float*)d_in[17];
  const float* e1w = (const float*)d_in[18];
  const float* e1b = (const float*)d_in[19];
  const float* e2w = (const float*)d_in[20];
  const float* e2b = (const float*)d_in[21];
  const float* ipw = (const float*)d_in[22];
  const float* ipb = (const float*)d_in[23];
  const float* opw = (const float*)d_in[24];
  const float* opb = (const float*)d_in[25];
  const float* saw = (const float*)d_in[26];
  const float* sab = (const float*)d_in[27];
  const float* plw = (const float*)d_in[28];
  const float* plb = (const float*)d_in[29];
  const float* wih = (const float*)d_in[30];
  const float* whh = (const float*)d_in[31];
  const float* bih = (const float*)d_in[32];
  const float* bhh = (const float*)d_in[33];
  const float* hw  = (const float*)d_in[34];
  const float* hb  = (const float*)d_in[35];
  float* ws  = (float*)d_ws;
  float* out = (float*)d_out;

  k_prep<<<256, 256, 0, stream>>>(self_w, self_b, e0w, e0b, e1w, e1b, e2w, e2b,
                                  ipw, opw, saw, plw, wih, bih, bhh, ws);
  k_assemble<<<2048, 256, 0, stream>>>(x_agent, x_lidar, x_safe, lw, lb, ws + X_OFF);
  {
    dim3 g(64, 4);
    k_gemm64<<<g, 256, 0, stream>>>(ws + X_OFF, ws + WP_OFF, ws + BP_OFF, ws + P_OFF, 256, 290, 64);
  }
  k_attn<<<4096, 256, 0, stream>>>(ws + P_OFF, ef0, ef1, ef2, em0, em1, em2,
                                   ws + WF_OFF,
                                   (const unsigned short*)(ws + WQKV_OFF),
                                   (const unsigned short*)(ws + WO_OFF),
                                   (const unsigned short*)(ws + WSA_OFF),
                                   ipb, opb, sab, ws + Y_OFF);
  {
    dim3 g(64, 2);
    k_gemm_pool<<<g, 256, 0, stream>>>(ws + X_OFF, ws + Y_OFF, ws + PW_OFF, plb, ws + Z_OFF);
  }
  {
    dim3 g(64, 8);
    k_gemm64<<<g, 256, 0, stream>>>(ws + Z_OFF, ws + WIH_OFF, ws + BG_OFF, ws + GX_OFF, 512, 128, 0);
  }
  k_lstm<<<128, 512, 0, stream>>>(ws + GX_OFF, whh, done, h0, c0, hw, hb, out);
}

// Round 11
// 293.569 us; speedup vs baseline: 2.1720x; 1.5290x over previous
//
#include <hip/hip_runtime.h>
#include <math.h>

// ---------------- workspace layout (float offsets) ----------------
// Time-shared region [0, 2621440): phase1 = XC(hi/lo) + P, phase2 = GX.
constexpr size_t XCH_OFF  = 0;         // ushort[4096*384]
constexpr size_t XCL_OFF  = 786432;    // ushort[4096*384]
constexpr size_t P_OFF    = 1572864;   // float[4096*256]
constexpr size_t GX_OFF   = 0;         // float[4096*512]  (overlays XC/P, disjoint in time)
constexpr size_t WPH_OFF  = 2621440;   // ushort frags 16ct x 10kt x 512
constexpr size_t WPL_OFF  = 2662400;
constexpr size_t BP_OFF   = 2703360;   // 256 fl
constexpr size_t WF_OFF   = 2703616;   // 4608 fl
constexpr size_t QKV_OFF  = 2708224;   // ushort 12288
constexpr size_t WO_OFF   = 2714368;   // ushort 4096
constexpr size_t WSA_OFF  = 2716416;   // ushort 4096
constexpr size_t PWH_OFF  = 2718464;   // ushort frags 8ct x 12kt x 512
constexpr size_t PWL_OFF  = 2743040;
constexpr size_t ZH_OFF   = 2767616;   // ushort[4096*128]
constexpr size_t ZL_OFF   = 3029760;
constexpr size_t WIHH_OFF = 3291904;   // ushort frags 32ct x 4kt x 512
constexpr size_t WIHL_OFF = 3324672;
constexpr size_t BG_OFF   = 3357440;   // 512 fl

typedef float f32x4 __attribute__((ext_vector_type(4)));
typedef __bf16 bf16x8v __attribute__((ext_vector_type(8)));
typedef unsigned short us8 __attribute__((ext_vector_type(8)));
union b8u { us8 u; bf16x8v b; };

static __device__ __forceinline__ float sigf(float x) { return 1.0f / (1.0f + __expf(-x)); }

static __device__ __forceinline__ unsigned short f2b(float x) {
  unsigned int u = __float_as_uint(x);
  unsigned int r = (u + 0x7FFFu + ((u >> 16) & 1u)) >> 16;
  return (unsigned short)r;
}
static __device__ __forceinline__ float b2f(unsigned short s) {
  return __uint_as_float(((unsigned int)s) << 16);
}
static __device__ __forceinline__ bf16x8v ld_bf8(const unsigned short* p) {
  b8u c; c.u = *(const us8*)p; return c.b;
}

// ---------------- prep: fold weights into split-bf16 MFMA B-fragments ----------------
// MFMA 16x16x32 bf16 fragment convention (verified r4, absmax 1.2e-4):
//   A: lane l holds A[row=l&15][k=8*(l>>4)+j]   B: lane l holds B[k=8*(l>>4)+j][col=l&15]
//   D: lane l holds D[row=4*(l>>4)+i][col=l&15]
__global__ __launch_bounds__(256) void k_prep(
    const float* __restrict__ self_w, const float* __restrict__ self_b,
    const float* __restrict__ e0w, const float* __restrict__ e0b,
    const float* __restrict__ e1w, const float* __restrict__ e1b,
    const float* __restrict__ e2w, const float* __restrict__ e2b,
    const float* __restrict__ ipw, const float* __restrict__ opw,
    const float* __restrict__ saw, const float* __restrict__ plw,
    const float* __restrict__ wih, const float* __restrict__ bih,
    const float* __restrict__ bhh, float* __restrict__ ws)
{
  unsigned short* WPH  = (unsigned short*)(ws + WPH_OFF);
  unsigned short* WPL  = (unsigned short*)(ws + WPL_OFF);
  unsigned short* QKVF = (unsigned short*)(ws + QKV_OFF);
  unsigned short* WOF  = (unsigned short*)(ws + WO_OFF);
  unsigned short* WSAF = (unsigned short*)(ws + WSA_OFF);
  unsigned short* PWH  = (unsigned short*)(ws + PWH_OFF);
  unsigned short* PWL  = (unsigned short*)(ws + PWL_OFF);
  unsigned short* WIHH = (unsigned short*)(ws + WIHH_OFF);
  unsigned short* WIHL = (unsigned short*)(ws + WIHL_OFF);
  const int N_WP = 16 * 10 * 512, N_PW = 8 * 12 * 512, N_WIH = 32 * 4 * 512;
  const int total = N_WP + 256 + 4608 + 12288 + 4096 + 4096 + N_PW + N_WIH + 512;
  for (int idx = blockIdx.x * 256 + threadIdx.x; idx < total; idx += gridDim.x * 256) {
    int i = idx;
    if (i < N_WP) {                        // P-GEMM B frags (Kpad=320, K=290)
      int ct = i / (10 * 512), rem = i % (10 * 512);
      int ktg = rem >> 9, e = rem & 511, ll = e >> 3, j = e & 7;
      int k = ktg * 32 + 8 * (ll >> 4) + j;
      int n = ct * 16 + (ll & 15);
      float v = 0.f;
      if (k < 290) {
        if (n < 64)       v = self_w[n * 580 + k] + self_w[n * 580 + 290 + k];
        else if (n < 128) v = e0w[(n - 64) * 306 + 16 + k];
        else if (n < 192) v = e1w[(n - 128) * 314 + 24 + k];
        else              v = e2w[(n - 192) * 322 + 32 + k];
      }
      unsigned short h = f2b(v);
      WPH[i] = h; WPL[i] = f2b(v - b2f(h)); continue;
    }
    i -= N_WP;
    if (i < 256) {                         // b_P
      float v;
      if (i < 64) v = self_b[i];
      else if (i < 128) v = e0b[i - 64];
      else if (i < 192) v = e1b[i - 128];
      else v = e2b[i - 192];
      ws[BP_OFF + i] = v; continue;
    }
    i -= 256;
    if (i < 4608) {                        // WF transposed [d][64], per type
      float v;
      if (i < 1024)      { int d = i >> 6, n = i & 63; v = e0w[n * 306 + d]; }
      else if (i < 2560) { int q = i - 1024, d = q >> 6, n = q & 63; v = e1w[n * 314 + d]; }
      else               { int q = i - 2560, d = q >> 6, n = q & 63; v = e2w[n * 322 + d]; }
      ws[WF_OFF + i] = v; continue;
    }
    i -= 4608;
    if (i < 12288) {                       // qkv in_proj frags (plain bf16)
      int ct = i >> 10, kt = (i >> 9) & 1, ll = (i >> 3) & 63, j = i & 7;
      int d = kt * 32 + 8 * (ll >> 4) + j;
      int n = ct * 16 + (ll & 15);
      QKVF[i] = f2b(ipw[n * 64 + d]); continue;
    }
    i -= 12288;
    if (i < 4096) {
      int ct = i >> 10, kt = (i >> 9) & 1, ll = (i >> 3) & 63, j = i & 7;
      int d = kt * 32 + 8 * (ll >> 4) + j;
      int n = ct * 16 + (ll & 15);
      WOF[i] = f2b(opw[n * 64 + d]); continue;
    }
    i -= 4096;
    if (i < 4096) {
      int ct = i >> 10, kt = (i >> 9) & 1, ll = (i >> 3) & 63, j = i & 7;
      int d = kt * 32 + 8 * (ll >> 4) + j;
      int n = ct * 16 + (ll & 15);
      WSAF[i] = f2b(saw[n * 64 + d]); continue;
    }
    i -= 4096;
    if (i < N_PW) {                        // pool B frags (Kpad=384, K=354)
      int ct = i / (12 * 512), rem = i % (12 * 512);
      int ktg = rem >> 9, e = rem & 511, ll = e >> 3, j = e & 7;
      int k = ktg * 32 + 8 * (ll >> 4) + j;
      int n = ct * 16 + (ll & 15);
      float v = (k < 354) ? plw[n * 354 + k] : 0.f;
      unsigned short h = f2b(v);
      PWH[i] = h; PWL[i] = f2b(v - b2f(h)); continue;
    }
    i -= N_PW;
    if (i < N_WIH) {                       // w_ih frags (K=128)
      int ct = i / (4 * 512), rem = i % (4 * 512);
      int ktg = rem >> 9, e = rem & 511, ll = e >> 3, j = e & 7;
      int k = ktg * 32 + 8 * (ll >> 4) + j;
      int n = ct * 16 + (ll & 15);
      float v = wih[n * 128 + k];
      unsigned short h = f2b(v);
      WIHH[i] = h; WIHL[i] = f2b(v - b2f(h)); continue;
    }
    i -= N_WIH;
    ws[BG_OFF + i] = bih[i] + bhh[i];
  }
}

// ---------------- conv + x_self assembly -> split-bf16 XC[4096][384] ----------------
__global__ __launch_bounds__(256) void k_assemble(
    const float* __restrict__ xa, const float* __restrict__ xl, const float* __restrict__ xs,
    const float* __restrict__ lw, const float* __restrict__ lb,
    unsigned short* __restrict__ xch, unsigned short* __restrict__ xcl)
{
  const int total = 4096 * 320;
  for (int idx = blockIdx.x * 256 + threadIdx.x; idx < total; idx += gridDim.x * 256) {
    int m = idx / 320, j = idx - m * 320;
    if (j >= 290) {                      // zero tail pad cols 354..383
      int c = 354 + (j - 290);
      xch[(size_t)m * 384 + c] = 0; xcl[(size_t)m * 384 + c] = 0; continue;
    }
    float v;
    if (j < 16) v = xa[m * 16 + j];
    else if (j < 286) {
      int jj = j - 16; int c = jj / 30; int p = jj - c * 30;
      const float* xr = xl + m * 32 + p;
      v = lw[c * 3] * xr[0] + lw[c * 3 + 1] * xr[1] + lw[c * 3 + 2] * xr[2] + lb[c];
      v = fmaxf(v, 0.f);
    } else v = xs[m * 4 + (j - 286)];
    unsigned short h = f2b(v);
    xch[(size_t)m * 384 + j] = h;
    xcl[(size_t)m * 384 + j] = f2b(v - b2f(h));
  }
}

// ---------------- split-bf16 MFMA GEMM ----------------
__global__ __launch_bounds__(256) void k_bgemm(
    const unsigned short* __restrict__ Ah, const unsigned short* __restrict__ Al, int ldaK,
    const unsigned short* __restrict__ Bh, const unsigned short* __restrict__ Bl,
    const float* __restrict__ bias, int Kpad, int N, int reluN,
    float* __restrict__ Cf, unsigned short* __restrict__ Chi, unsigned short* __restrict__ Clo,
    int mode)
{
  __shared__ unsigned short AhS[64 * 72], AlS[64 * 72];
  int m0 = blockIdx.x * 64;
  int tid = threadIdx.x, w = tid >> 6, l = tid & 63, lr = l & 15, lg = l >> 4;
  int ctg = blockIdx.y * 4 + w;
  int nKt = Kpad >> 5;
  f32x4 acc[4] = {};
  int srow = tid >> 2, sseg = tid & 3;
  for (int k0 = 0; k0 < Kpad; k0 += 64) {
    {
      const us8* gh = (const us8*)&Ah[(size_t)(m0 + srow) * ldaK + k0 + sseg * 16];
      const us8* gl_ = (const us8*)&Al[(size_t)(m0 + srow) * ldaK + k0 + sseg * 16];
      us8 h0 = gh[0], h1 = gh[1], l0 = gl_[0], l1 = gl_[1];
      *(us8*)&AhS[srow * 72 + sseg * 16]     = h0;
      *(us8*)&AhS[srow * 72 + sseg * 16 + 8] = h1;
      *(us8*)&AlS[srow * 72 + sseg * 16]     = l0;
      *(us8*)&AlS[srow * 72 + sseg * 16 + 8] = l1;
    }
    __syncthreads();
    #pragma unroll
    for (int kt = 0; kt < 2; ++kt) {
      int ktg = (k0 >> 5) + kt;
      bf16x8v bh = ld_bf8(&Bh[((size_t)(ctg * nKt + ktg) * 64 + l) * 8]);
      bf16x8v bl = ld_bf8(&Bl[((size_t)(ctg * nKt + ktg) * 64 + l) * 8]);
      #pragma unroll
      for (int rt = 0; rt < 4; ++rt) {
        bf16x8v ah = ld_bf8(&AhS[(rt * 16 + lr) * 72 + kt * 32 + 8 * lg]);
        bf16x8v al = ld_bf8(&AlS[(rt * 16 + lr) * 72 + kt * 32 + 8 * lg]);
        acc[rt] = __builtin_amdgcn_mfma_f32_16x16x32_bf16(ah, bh, acc[rt], 0, 0, 0);
        acc[rt] = __builtin_amdgcn_mfma_f32_16x16x32_bf16(al, bh, acc[rt], 0, 0, 0);
        acc[rt] = __builtin_amdgcn_mfma_f32_16x16x32_bf16(ah, bl, acc[rt], 0, 0, 0);
      }
    }
    __syncthreads();
  }
  int n = ctg * 16 + lr;
  float bs = bias[n];
  #pragma unroll
  for (int rt = 0; rt < 4; ++rt) {
    #pragma unroll
    for (int i = 0; i < 4; ++i) {
      int row = m0 + rt * 16 + lg * 4 + i;
      float v = acc[rt][i] + bs;
      if (n < reluN) v = fmaxf(v, 0.f);
      if (mode == 0) Cf[(size_t)row * N + n] = v;
      else {
        unsigned short h = f2b(v);
        Chi[(size_t)row * N + n] = h;
        Clo[(size_t)row * N + n] = f2b(v - b2f(h));
      }
    }
  }
}

// ---------------- entity-row encoder: bf16 rows into zh (stride 72, rows 1..48) ----------------
template <int DK>
static __device__ __forceinline__ void ent_encode(
    const float* __restrict__ fP, const float* __restrict__ WF,
    const float* __restrict__ xsP, unsigned short* __restrict__ zh, int m, int w, int l, int t)
{
  float wreg[DK];
  #pragma unroll
  for (int d = 0; d < DK; ++d) wreg[d] = WF[d * 64 + l];
  float xb = xsP[64 + t * 64 + l];
  #pragma unroll
  for (int i = 0; i < 4; ++i) {
    int er = w + 4 * i;
    const float* fr = fP + (size_t)(m * 16 + er) * DK;
    float acc = xb;
    #pragma unroll
    for (int d4 = 0; d4 < DK / 4; ++d4) {
      float4 f4 = reinterpret_cast<const float4*>(fr)[d4];
      acc += f4.x * wreg[4 * d4] + f4.y * wreg[4 * d4 + 1] + f4.z * wreg[4 * d4 + 2] + f4.w * wreg[4 * d4 + 3];
    }
    zh[(1 + t * 16 + er) * 72 + l] = f2b(fmaxf(acc, 0.f));
  }
}

// ---------------- fused entity + MFMA attention (swapped QK^T + MFMA PV) ----------------
// LDS 53,712 B -> 3 blocks/CU. Hand-packed overlays:
//   phase A: zh | qh kh xsP | vt | sah      phase B: P overlays qh/kh/xsP
__global__ __launch_bounds__(256, 3) void k_attn(
    const float* __restrict__ Pmat,
    const float* __restrict__ f0, const float* __restrict__ f1, const float* __restrict__ f2,
    const float* __restrict__ mk0, const float* __restrict__ mk1, const float* __restrict__ mk2,
    const float* __restrict__ WF,
    const unsigned short* __restrict__ QKVF,
    const unsigned short* __restrict__ WOF,
    const unsigned short* __restrict__ WSAF,
    const float* __restrict__ ipb, const float* __restrict__ opb, const float* __restrict__ sab_,
    unsigned short* __restrict__ xch, unsigned short* __restrict__ xcl)
{
  __shared__ unsigned short smem[26856];        // 53,712 B
  unsigned short* zh  = smem;                   // [49][72]
  unsigned short* qh  = smem + 3528;            // [64][72] (phase A)
  unsigned short* kh  = smem + 8136;            // [64][72] (phase A)
  float*          xsP = (float*)(smem + 12744); // [256]    (phase A early)
  unsigned short* pl  = smem + 3528;            // [4][49][72] P (phase B overlay)
  unsigned short* vt  = smem + 17640;           // [4][16][72] V^T
  unsigned short* sah = smem + 22248;           // [64][72] attn out
  unsigned short* oh  = kh;                     // [64][72] out_proj (phase C overlay)
  int m = blockIdx.x;
  int tid = threadIdx.x, w = tid >> 6, l = tid & 63;
  int lr = l & 15, lg = l >> 4;
  b8u zz;
  #pragma unroll
  for (int i = 0; i < 8; ++i) zz.u[i] = 0;
  bf16x8v zero8 = zz.b;

  // --- C0: P row -> xsP + zh row0; per-lane mask regs (key = rt*16+4*lg+ii) ---
  float mvr[16];
  {
    float pv = Pmat[(size_t)m * 256 + tid];
    xsP[tid] = pv;
    if (tid < 64) zh[tid] = f2b(pv);
    #pragma unroll
    for (int rt = 0; rt < 4; ++rt)
      #pragma unroll
      for (int ii = 0; ii < 4; ++ii) {
        int key = rt * 16 + 4 * lg + ii;
        float v;
        if (key == 0) v = 1.f;
        else if (key < 17) v = mk0[m * 16 + key - 1];
        else if (key < 33) v = mk1[m * 16 + key - 17];
        else if (key < 49) v = mk2[m * 16 + key - 33];
        else v = 0.f;
        mvr[rt * 4 + ii] = v;
      }
  }
  __syncthreads();

  // --- C1: entity rows 1..48 ---
  ent_encode<16>(f0, WF + 0,    xsP, zh, m, w, l, 0);
  ent_encode<24>(f1, WF + 1024, xsP, zh, m, w, l, 1);
  ent_encode<32>(f2, WF + 2560, xsP, zh, m, w, l, 2);
  __syncthreads();

  // --- C2: q,k,v = z @ Wqkv + b; writes ALL 64 rows (rows>=49 = bias, finite) ---
  {
    bf16x8v za[4][2];
    #pragma unroll
    for (int rt = 0; rt < 4; ++rt)
      #pragma unroll
      for (int kt = 0; kt < 2; ++kt) {
        bf16x8v t = ld_bf8(&zh[(rt * 16 + lr) * 72 + kt * 32 + 8 * lg]);  // rows>=49 alias qh: select zero
        za[rt][kt] = (rt * 16 + lr < 49) ? t : zero8;
      }
    #pragma unroll
    for (int cc = 0; cc < 3; ++cc) {
      int ct = w + 4 * cc;
      bf16x8v b0 = ld_bf8(&QKVF[((ct * 2 + 0) * 64 + l) * 8]);
      bf16x8v b1 = ld_bf8(&QKVF[((ct * 2 + 1) * 64 + l) * 8]);
      int n = ct * 16 + lr;
      float bias = ipb[n];
      #pragma unroll
      for (int rt = 0; rt < 4; ++rt) {
        f32x4 acc = {0.f, 0.f, 0.f, 0.f};
        acc = __builtin_amdgcn_mfma_f32_16x16x32_bf16(za[rt][0], b0, acc, 0, 0, 0);
        acc = __builtin_amdgcn_mfma_f32_16x16x32_bf16(za[rt][1], b1, acc, 0, 0, 0);
        #pragma unroll
        for (int i = 0; i < 4; ++i) {
          int r = rt * 16 + lg * 4 + i;
          float val = acc[i] + bias;
          if (cc == 0)      qh[r * 72 + n] = f2b(val);
          else if (cc == 1) kh[r * 72 + (n - 64)] = f2b(val);
          else { int hd = n - 128; vt[(hd >> 4) * 1152 + (hd & 15) * 72 + r] = f2b(val); }
        }
      }
    }
  }
  __syncthreads();

  // --- C3: S^T = K·Q^T (d 16->32 zero-pad), reg softmax, P->LDS, PV = V^T·P^T ---
  float pst[4][16];   // [ct][key-slot]: scores -> normalized probs
  {
    int h = w;
    bf16x8v ka[4], qb[4];
    #pragma unroll
    for (int rt = 0; rt < 4; ++rt) {
      bf16x8v t = ld_bf8(&kh[(rt * 16 + lr) * 72 + h * 16 + 8 * (lg & 1)]);
      ka[rt] = (lg < 2) ? t : zero8;          // k-chunks d16..31 are zero-pad
    }
    #pragma unroll
    for (int ct = 0; ct < 4; ++ct) {
      bf16x8v t = ld_bf8(&qh[(ct * 16 + lr) * 72 + h * 16 + 8 * (lg & 1)]);
      qb[ct] = (lg < 2) ? t : zero8;
    }
    #pragma unroll
    for (int ct = 0; ct < 4; ++ct)
      #pragma unroll
      for (int rt = 0; rt < 4; ++rt) {
        f32x4 acc = {0.f, 0.f, 0.f, 0.f};
        acc = __builtin_amdgcn_mfma_f32_16x16x32_bf16(ka[rt], qb[ct], acc, 0, 0, 0);
        #pragma unroll
        for (int i = 0; i < 4; ++i) pst[ct][rt * 4 + i] = acc[i];
      }
    // masked softmax per query q = ct*16+lr (keys spread over lg x regs)
    #pragma unroll
    for (int ct = 0; ct < 4; ++ct) {
      float mx = -1e30f;
      #pragma unroll
      for (int k16 = 0; k16 < 16; ++k16) {
        float x = pst[ct][k16] * 0.25f;
        pst[ct][k16] = x;
        if (mvr[k16] != 0.f) mx = fmaxf(mx, x);
      }
      mx = fmaxf(mx, __shfl_xor(mx, 16, 64));
      mx = fmaxf(mx, __shfl_xor(mx, 32, 64));
      float sum = 0.f;
      #pragma unroll
      for (int k16 = 0; k16 < 16; ++k16) {
        float p = (mvr[k16] != 0.f) ? __expf(pst[ct][k16] - mx) : 0.f;
        pst[ct][k16] = p;
        sum += p;
      }
      sum += __shfl_xor(sum, 16, 64);
      sum += __shfl_xor(sum, 32, 64);
      float inv = 1.f / sum;
      #pragma unroll
      for (int k16 = 0; k16 < 16; ++k16) pst[ct][k16] *= inv;
    }
  }
  __syncthreads();                       // all qh/kh reads complete before P overlay
  {
    int h = w;
    unsigned short* ph = pl + h * 3528;  // [49][72]; rows>=49 unwritten (read-finite spill)
    #pragma unroll
    for (int ct = 0; ct < 4; ++ct) {
      int q = ct * 16 + lr;
      if (q < 49) {
        #pragma unroll
        for (int rt = 0; rt < 4; ++rt)
          #pragma unroll
          for (int ii = 0; ii < 4; ++ii)
            ph[q * 72 + rt * 16 + 4 * lg + ii] = f2b(pst[ct][rt * 4 + ii]);
      }
    }
  }
  __syncthreads();                       // P visible
  {
    int h = w;
    const unsigned short* ph = pl + h * 3528;
    bf16x8v va0 = ld_bf8(&vt[h * 1152 + lr * 72 + 8 * lg]);        // V^T[d=lr][keys 8lg..]
    bf16x8v va1 = ld_bf8(&vt[h * 1152 + lr * 72 + 32 + 8 * lg]);
    #pragma unroll
    for (int ct = 0; ct < 4; ++ct) {
      bf16x8v pb0 = ld_bf8(&ph[(ct * 16 + lr) * 72 + 8 * lg]);     // P^T[key][q=ct*16+lr]
      bf16x8v pb1 = ld_bf8(&ph[(ct * 16 + lr) * 72 + 32 + 8 * lg]);
      f32x4 o = {0.f, 0.f, 0.f, 0.f};
      o = __builtin_amdgcn_mfma_f32_16x16x32_bf16(va0, pb0, o, 0, 0, 0);
      o = __builtin_amdgcn_mfma_f32_16x16x32_bf16(va1, pb1, o, 0, 0, 0);
      int q = ct * 16 + lr;              // D[d=4*lg+i][q]
      #pragma unroll
      for (int i = 0; i < 4; ++i)
        sah[q * 72 + h * 16 + 4 * lg + i] = f2b(o[i]);
    }
  }
  __syncthreads();

  // --- C4: o = sa @ Wo + b (oh overlays kh; P dead) ---
  {
    int ct = w, n = ct * 16 + lr;
    bf16x8v b0 = ld_bf8(&WOF[((ct * 2 + 0) * 64 + l) * 8]);
    bf16x8v b1 = ld_bf8(&WOF[((ct * 2 + 1) * 64 + l) * 8]);
    float bias = opb[n];
    #pragma unroll
    for (int rt = 0; rt < 4; ++rt) {
      bf16x8v a0 = ld_bf8(&sah[(rt * 16 + lr) * 72 + 8 * lg]);
      bf16x8v a1 = ld_bf8(&sah[(rt * 16 + lr) * 72 + 32 + 8 * lg]);
      f32x4 acc = {0.f, 0.f, 0.f, 0.f};
      acc = __builtin_amdgcn_mfma_f32_16x16x32_bf16(a0, b0, acc, 0, 0, 0);
      acc = __builtin_amdgcn_mfma_f32_16x16x32_bf16(a1, b1, acc, 0, 0, 0);
      #pragma unroll
      for (int i = 0; i < 4; ++i) {
        int r = rt * 16 + lg * 4 + i;
        if (r < 49) oh[r * 72 + n] = f2b(acc[i] + bias);
      }
    }
  }
  __syncthreads();

  // --- C5: res = z + relu(o @ Wsa + b); masked mean (mvr regs); split-bf16 out ---
  {
    int ct = w, n = ct * 16 + lr;
    bf16x8v b0 = ld_bf8(&WSAF[((ct * 2 + 0) * 64 + l) * 8]);
    bf16x8v b1 = ld_bf8(&WSAF[((ct * 2 + 1) * 64 + l) * 8]);
    float bias = sab_[n];
    float pacc = 0.f;
    #pragma unroll
    for (int rt = 0; rt < 4; ++rt) {
      bf16x8v a0 = ld_bf8(&oh[(rt * 16 + lr) * 72 + 8 * lg]);
      bf16x8v a1 = ld_bf8(&oh[(rt * 16 + lr) * 72 + 32 + 8 * lg]);
      f32x4 acc = {0.f, 0.f, 0.f, 0.f};
      acc = __builtin_amdgcn_mfma_f32_16x16x32_bf16(a0, b0, acc, 0, 0, 0);
      acc = __builtin_amdgcn_mfma_f32_16x16x32_bf16(a1, b1, acc, 0, 0, 0);
      #pragma unroll
      for (int i = 0; i < 4; ++i) {
        int r = rt * 16 + lg * 4 + i;
        if (r < 49) {
          float val = fmaxf(acc[i] + bias, 0.f);
          float z = b2f(zh[r * 72 + n]);
          pacc += (z + val) * mvr[rt * 4 + i];   // mvr slot key == r
        }
      }
    }
    pacc += __shfl_xor(pacc, 16, 64);
    pacc += __shfl_xor(pacc, 32, 64);
    if (lg == 0) {
      float y = pacc * (1.0f / 49.0f);
      unsigned short h = f2b(y);
      xch[(size_t)m * 384 + 290 + n] = h;
      xcl[(size_t)m * 384 + 290 + n] = f2b(y - b2f(h));
    }
  }
}

// ---------------- LSTM scan + value head ----------------
__global__ __launch_bounds__(512) void k_lstm(
    const float* __restrict__ Gx, const float* __restrict__ whh,
    const float* __restrict__ done, const float* __restrict__ h0, const float* __restrict__ c0,
    const float* __restrict__ hw, const float* __restrict__ hb, float* __restrict__ out)
{
  __shared__ float h[128], c[128], gl[512], red[2];
  int s = blockIdx.x, b = s >> 3;
  int g = threadIdx.x;
  float wreg[128];
  {
    const float4* w4 = reinterpret_cast<const float4*>(whh + (size_t)g * 128);
    #pragma unroll
    for (int j4 = 0; j4 < 32; ++j4) {
      float4 f4 = w4[j4];
      wreg[4 * j4] = f4.x; wreg[4 * j4 + 1] = f4.y; wreg[4 * j4 + 2] = f4.z; wreg[4 * j4 + 3] = f4.w;
    }
  }
  if (g < 128) { h[g] = h0[s * 128 + g]; c[g] = c0[s * 128 + g]; }
  __syncthreads();
  for (int t = 0; t < 32; ++t) {
    float keep = 1.f - done[t * 16 + b];
    float acc = 0.f;
    const float4* h4 = reinterpret_cast<const float4*>(h);
    #pragma unroll
    for (int j4 = 0; j4 < 32; ++j4) {
      float4 f4 = h4[j4];
      acc += f4.x * wreg[4 * j4] + f4.y * wreg[4 * j4 + 1] + f4.z * wreg[4 * j4 + 2] + f4.w * wreg[4 * j4 + 3];
    }
    gl[g] = Gx[(size_t)(t * 128 + s) * 512 + g] + keep * acc;
    __syncthreads();
    if (g < 128) {
      float iv = sigf(gl[g]);
      float fv = sigf(gl[128 + g]);
      float gg = tanhf(gl[256 + g]);
      float ov = sigf(gl[384 + g]);
      float cn = fv * (c[g] * keep) + iv * gg;
      float hn = ov * tanhf(cn);
      c[g] = cn; h[g] = hn;
      float pv = hn * hw[g];
      #pragma unroll
      for (int off = 32; off > 0; off >>= 1) pv += __shfl_down(pv, off, 64);
      if ((g & 63) == 0) red[g >> 6] = pv;
    }
    __syncthreads();
    if (g == 0) out[t * 128 + s] = red[0] + red[1] + hb[0];
  }
}

// ---------------- launch ----------------
extern "C" void kernel_launch(void* const* d_in, const int* in_sizes, int n_in,
                              void* d_out, int out_size, void* d_ws, size_t ws_size,
                              hipStream_t stream) {
  const float* x_agent = (const float*)d_in[0];
  const float* x_lidar = (const float*)d_in[1];
  const float* x_safe  = (const float*)d_in[2];
  const float* ef0 = (const float*)d_in[3];
  const float* em0 = (const float*)d_in[4];
  const float* ef1 = (const float*)d_in[5];
  const float* em1 = (const float*)d_in[6];
  const float* ef2 = (const float*)d_in[7];
  const float* em2 = (const float*)d_in[8];
  const float* done = (const float*)d_in[9];
  const float* h0 = (const float*)d_in[10];
  const float* c0 = (const float*)d_in[11];
  const float* lw = (const float*)d_in[12];
  const float* lb = (const float*)d_in[13];
  const float* self_w = (const float*)d_in[14];
  const float* self_b = (const float*)d_in[15];
  const float* e0w = (const float*)d_in[16];
  const float* e0b = (const float*)d_in[17];
  const float* e1w = (const float*)d_in[18];
  const float* e1b = (const float*)d_in[19];
  const float* e2w = (const float*)d_in[20];
  const float* e2b = (const float*)d_in[21];
  const float* ipw = (const float*)d_in[22];
  const float* ipb = (const float*)d_in[23];
  const float* opw = (const float*)d_in[24];
  const float* opb = (const float*)d_in[25];
  const float* saw = (const float*)d_in[26];
  const float* sab = (const float*)d_in[27];
  const float* plw = (const float*)d_in[28];
  const float* plb = (const float*)d_in[29];
  const float* wih = (const float*)d_in[30];
  const float* whh = (const float*)d_in[31];
  const float* bih = (const float*)d_in[32];
  const float* bhh = (const float*)d_in[33];
  const float* hw  = (const float*)d_in[34];
  const float* hb  = (const float*)d_in[35];
  float* ws  = (float*)d_ws;
  float* out = (float*)d_out;

  unsigned short* XCH = (unsigned short*)(ws + XCH_OFF);
  unsigned short* XCL = (unsigned short*)(ws + XCL_OFF);

  k_prep<<<256, 256, 0, stream>>>(self_w, self_b, e0w, e0b, e1w, e1b, e2w, e2b,
                                  ipw, opw, saw, plw, wih, bih, bhh, ws);
  k_assemble<<<2048, 256, 0, stream>>>(x_agent, x_lidar, x_safe, lw, lb, XCH, XCL);
  {
    dim3 g(64, 4);   // P = XC(:, :290) @ WP + bP; relu on cols < 64
    k_bgemm<<<g, 256, 0, stream>>>(XCH, XCL, 384,
                                   (const unsigned short*)(ws + WPH_OFF),
                                   (const unsigned short*)(ws + WPL_OFF),
                                   ws + BP_OFF, 320, 256, 64,
                                   ws + P_OFF, nullptr, nullptr, 0);
  }
  k_attn<<<4096, 256, 0, stream>>>(ws + P_OFF, ef0, ef1, ef2, em0, em1, em2,
                                   ws + WF_OFF,
                                   (const unsigned short*)(ws + QKV_OFF),
                                   (const unsigned short*)(ws + WO_OFF),
                                   (const unsigned short*)(ws + WSA_OFF),
                                   ipb, opb, sab, XCH, XCL);
  {
    dim3 g(64, 2);   // Z = relu([X | z_pool] @ plw^T + plb), split-bf16 out
    k_bgemm<<<g, 256, 0, stream>>>(XCH, XCL, 384,
                                   (const unsigned short*)(ws + PWH_OFF),
                                   (const unsigned short*)(ws + PWL_OFF),
                                   plb, 384, 128, 128,
                                   nullptr,
                                   (unsigned short*)(ws + ZH_OFF),
                                   (unsigned short*)(ws + ZL_OFF), 1);
  }
  {
    dim3 g(64, 8);   // Gx = Z @ w_ih^T + (b_ih + b_hh), fp32 out
    k_bgemm<<<g, 256, 0, stream>>>((const unsigned short*)(ws + ZH_OFF),
                                   (const unsigned short*)(ws + ZL_OFF), 128,
                                   (const unsigned short*)(ws + WIHH_OFF),
                                   (const unsigned short*)(ws + WIHL_OFF),
                                   ws + BG_OFF, 128, 512, 0,
                                   ws + GX_OFF, nullptr, nullptr, 0);
  }
  k_lstm<<<128, 512, 0, stream>>>(ws + GX_OFF, whh, done, h0, c0, hw, hb, out);
}

// Round 12
// 280.542 us; speedup vs baseline: 2.2728x; 1.0464x over previous
//
#include <hip/hip_runtime.h>
#include <math.h>

// ---------------- workspace layout (float offsets) ----------------
// Time-shared region [0, 2621440): phase1 = XC(hi/lo) + P, phase2 = GX.
constexpr size_t XCH_OFF  = 0;         // ushort[4096*384]
constexpr size_t XCL_OFF  = 786432;    // ushort[4096*384]
constexpr size_t P_OFF    = 1572864;   // float[4096*256]
constexpr size_t GX_OFF   = 0;         // float[4096*512]  (overlays XC/P, disjoint in time)
constexpr size_t WPH_OFF  = 2621440;   // ushort frags 16ct x 10kt x 512
constexpr size_t WPL_OFF  = 2662400;
constexpr size_t BP_OFF   = 2703360;   // 256 fl
constexpr size_t WF_OFF   = 2703616;   // ushort frags 3t x 4ct x 512 = 6144 us (3072 fl)
constexpr size_t QKV_OFF  = 2708224;   // ushort 12288
constexpr size_t WO_OFF   = 2714368;   // ushort 4096
constexpr size_t WSA_OFF  = 2716416;   // ushort 4096
constexpr size_t PWH_OFF  = 2718464;   // ushort frags 8ct x 12kt x 512
constexpr size_t PWL_OFF  = 2743040;
constexpr size_t ZH_OFF   = 2767616;   // ushort[4096*128]
constexpr size_t ZL_OFF   = 3029760;
constexpr size_t WIHH_OFF = 3291904;   // ushort frags 32ct x 4kt x 512
constexpr size_t WIHL_OFF = 3324672;
constexpr size_t BG_OFF   = 3357440;   // 512 fl

typedef float f32x4 __attribute__((ext_vector_type(4)));
typedef __bf16 bf16x8v __attribute__((ext_vector_type(8)));
typedef unsigned short us8 __attribute__((ext_vector_type(8)));
union b8u { us8 u; bf16x8v b; };

static __device__ __forceinline__ float sigf(float x) { return 1.0f / (1.0f + __expf(-x)); }

static __device__ __forceinline__ unsigned short f2b(float x) {
  unsigned int u = __float_as_uint(x);
  unsigned int r = (u + 0x7FFFu + ((u >> 16) & 1u)) >> 16;
  return (unsigned short)r;
}
static __device__ __forceinline__ float b2f(unsigned short s) {
  return __uint_as_float(((unsigned int)s) << 16);
}
static __device__ __forceinline__ bf16x8v ld_bf8(const unsigned short* p) {
  b8u c; c.u = *(const us8*)p; return c.b;
}

// ---------------- prep: fold weights into split-bf16 MFMA B-fragments ----------------
// MFMA 16x16x32 bf16 fragment convention (verified r4/r11):
//   A: lane l holds A[row=l&15][k=8*(l>>4)+j]   B: lane l holds B[k=8*(l>>4)+j][col=l&15]
//   D: lane l holds D[row=4*(l>>4)+i][col=l&15]
__global__ __launch_bounds__(256) void k_prep(
    const float* __restrict__ self_w, const float* __restrict__ self_b,
    const float* __restrict__ e0w, const float* __restrict__ e0b,
    const float* __restrict__ e1w, const float* __restrict__ e1b,
    const float* __restrict__ e2w, const float* __restrict__ e2b,
    const float* __restrict__ ipw, const float* __restrict__ opw,
    const float* __restrict__ saw, const float* __restrict__ plw,
    const float* __restrict__ wih, const float* __restrict__ bih,
    const float* __restrict__ bhh, float* __restrict__ ws)
{
  unsigned short* WPH  = (unsigned short*)(ws + WPH_OFF);
  unsigned short* WPL  = (unsigned short*)(ws + WPL_OFF);
  unsigned short* WFF  = (unsigned short*)(ws + WF_OFF);
  unsigned short* QKVF = (unsigned short*)(ws + QKV_OFF);
  unsigned short* WOF  = (unsigned short*)(ws + WO_OFF);
  unsigned short* WSAF = (unsigned short*)(ws + WSA_OFF);
  unsigned short* PWH  = (unsigned short*)(ws + PWH_OFF);
  unsigned short* PWL  = (unsigned short*)(ws + PWL_OFF);
  unsigned short* WIHH = (unsigned short*)(ws + WIHH_OFF);
  unsigned short* WIHL = (unsigned short*)(ws + WIHL_OFF);
  const int N_WP = 16 * 10 * 512, N_PW = 8 * 12 * 512, N_WIH = 32 * 4 * 512;
  const int total = N_WP + 256 + 6144 + 12288 + 4096 + 4096 + N_PW + N_WIH + 512;
  for (int idx = blockIdx.x * 256 + threadIdx.x; idx < total; idx += gridDim.x * 256) {
    int i = idx;
    if (i < N_WP) {                        // P-GEMM B frags (Kpad=320, K=290)
      int ct = i / (10 * 512), rem = i % (10 * 512);
      int ktg = rem >> 9, e = rem & 511, ll = e >> 3, j = e & 7;
      int k = ktg * 32 + 8 * (ll >> 4) + j;
      int n = ct * 16 + (ll & 15);
      float v = 0.f;
      if (k < 290) {
        if (n < 64)       v = self_w[n * 580 + k] + self_w[n * 580 + 290 + k];
        else if (n < 128) v = e0w[(n - 64) * 306 + 16 + k];
        else if (n < 192) v = e1w[(n - 128) * 314 + 24 + k];
        else              v = e2w[(n - 192) * 322 + 32 + k];
      }
      unsigned short h = f2b(v);
      WPH[i] = h; WPL[i] = f2b(v - b2f(h)); continue;
    }
    i -= N_WP;
    if (i < 256) {                         // b_P
      float v;
      if (i < 64) v = self_b[i];
      else if (i < 128) v = e0b[i - 64];
      else if (i < 192) v = e1b[i - 128];
      else v = e2b[i - 192];
      ws[BP_OFF + i] = v; continue;
    }
    i -= 256;
    if (i < 6144) {                        // WFF: entity-feat B-frags [t][ct][l][8], K=32 pad
      int t2 = i >> 11, rem = i & 2047;
      int ct = rem >> 9, e = rem & 511, ll = e >> 3, j = e & 7;
      int k = 8 * (ll >> 4) + j;
      int n = ct * 16 + (ll & 15);
      float v = 0.f;
      if (t2 == 0)      { if (k < 16) v = e0w[n * 306 + k]; }
      else if (t2 == 1) { if (k < 24) v = e1w[n * 314 + k]; }
      else              { if (k < 32) v = e2w[n * 322 + k]; }
      WFF[i] = f2b(v); continue;
    }
    i -= 6144;
    if (i < 12288) {                       // qkv in_proj frags (plain bf16)
      int ct = i >> 10, kt = (i >> 9) & 1, ll = (i >> 3) & 63, j = i & 7;
      int d = kt * 32 + 8 * (ll >> 4) + j;
      int n = ct * 16 + (ll & 15);
      QKVF[i] = f2b(ipw[n * 64 + d]); continue;
    }
    i -= 12288;
    if (i < 4096) {
      int ct = i >> 10, kt = (i >> 9) & 1, ll = (i >> 3) & 63, j = i & 7;
      int d = kt * 32 + 8 * (ll >> 4) + j;
      int n = ct * 16 + (ll & 15);
      WOF[i] = f2b(opw[n * 64 + d]); continue;
    }
    i -= 4096;
    if (i < 4096) {
      int ct = i >> 10, kt = (i >> 9) & 1, ll = (i >> 3) & 63, j = i & 7;
      int d = kt * 32 + 8 * (ll >> 4) + j;
      int n = ct * 16 + (ll & 15);
      WSAF[i] = f2b(saw[n * 64 + d]); continue;
    }
    i -= 4096;
    if (i < N_PW) {                        // pool B frags (Kpad=384, K=354)
      int ct = i / (12 * 512), rem = i % (12 * 512);
      int ktg = rem >> 9, e = rem & 511, ll = e >> 3, j = e & 7;
      int k = ktg * 32 + 8 * (ll >> 4) + j;
      int n = ct * 16 + (ll & 15);
      float v = (k < 354) ? plw[n * 354 + k] : 0.f;
      unsigned short h = f2b(v);
      PWH[i] = h; PWL[i] = f2b(v - b2f(h)); continue;
    }
    i -= N_PW;
    if (i < N_WIH) {                       // w_ih frags (K=128)
      int ct = i / (4 * 512), rem = i % (4 * 512);
      int ktg = rem >> 9, e = rem & 511, ll = e >> 3, j = e & 7;
      int k = ktg * 32 + 8 * (ll >> 4) + j;
      int n = ct * 16 + (ll & 15);
      float v = wih[n * 128 + k];
      unsigned short h = f2b(v);
      WIHH[i] = h; WIHL[i] = f2b(v - b2f(h)); continue;
    }
    i -= N_WIH;
    ws[BG_OFF + i] = bih[i] + bhh[i];
  }
}

// ---------------- conv + x_self assembly -> split-bf16 XC[4096][384] ----------------
__global__ __launch_bounds__(256) void k_assemble(
    const float* __restrict__ xa, const float* __restrict__ xl, const float* __restrict__ xs,
    const float* __restrict__ lw, const float* __restrict__ lb,
    unsigned short* __restrict__ xch, unsigned short* __restrict__ xcl)
{
  const int total = 4096 * 320;
  for (int idx = blockIdx.x * 256 + threadIdx.x; idx < total; idx += gridDim.x * 256) {
    int m = idx / 320, j = idx - m * 320;
    if (j >= 290) {                      // zero tail pad cols 354..383
      int c = 354 + (j - 290);
      xch[(size_t)m * 384 + c] = 0; xcl[(size_t)m * 384 + c] = 0; continue;
    }
    float v;
    if (j < 16) v = xa[m * 16 + j];
    else if (j < 286) {
      int jj = j - 16; int c = jj / 30; int p = jj - c * 30;
      const float* xr = xl + m * 32 + p;
      v = lw[c * 3] * xr[0] + lw[c * 3 + 1] * xr[1] + lw[c * 3 + 2] * xr[2] + lb[c];
      v = fmaxf(v, 0.f);
    } else v = xs[m * 4 + (j - 286)];
    unsigned short h = f2b(v);
    xch[(size_t)m * 384 + j] = h;
    xcl[(size_t)m * 384 + j] = f2b(v - b2f(h));
  }
}

// ---------------- split-bf16 MFMA GEMM ----------------
__global__ __launch_bounds__(256) void k_bgemm(
    const unsigned short* __restrict__ Ah, const unsigned short* __restrict__ Al, int ldaK,
    const unsigned short* __restrict__ Bh, const unsigned short* __restrict__ Bl,
    const float* __restrict__ bias, int Kpad, int N, int reluN,
    float* __restrict__ Cf, unsigned short* __restrict__ Chi, unsigned short* __restrict__ Clo,
    int mode)
{
  __shared__ unsigned short AhS[64 * 72], AlS[64 * 72];
  int m0 = blockIdx.x * 64;
  int tid = threadIdx.x, w = tid >> 6, l = tid & 63, lr = l & 15, lg = l >> 4;
  int ctg = blockIdx.y * 4 + w;
  int nKt = Kpad >> 5;
  f32x4 acc[4] = {};
  int srow = tid >> 2, sseg = tid & 3;
  for (int k0 = 0; k0 < Kpad; k0 += 64) {
    {
      const us8* gh = (const us8*)&Ah[(size_t)(m0 + srow) * ldaK + k0 + sseg * 16];
      const us8* gl_ = (const us8*)&Al[(size_t)(m0 + srow) * ldaK + k0 + sseg * 16];
      us8 h0 = gh[0], h1 = gh[1], l0 = gl_[0], l1 = gl_[1];
      *(us8*)&AhS[srow * 72 + sseg * 16]     = h0;
      *(us8*)&AhS[srow * 72 + sseg * 16 + 8] = h1;
      *(us8*)&AlS[srow * 72 + sseg * 16]     = l0;
      *(us8*)&AlS[srow * 72 + sseg * 16 + 8] = l1;
    }
    __syncthreads();
    #pragma unroll
    for (int kt = 0; kt < 2; ++kt) {
      int ktg = (k0 >> 5) + kt;
      bf16x8v bh = ld_bf8(&Bh[((size_t)(ctg * nKt + ktg) * 64 + l) * 8]);
      bf16x8v bl = ld_bf8(&Bl[((size_t)(ctg * nKt + ktg) * 64 + l) * 8]);
      #pragma unroll
      for (int rt = 0; rt < 4; ++rt) {
        bf16x8v ah = ld_bf8(&AhS[(rt * 16 + lr) * 72 + kt * 32 + 8 * lg]);
        bf16x8v al = ld_bf8(&AlS[(rt * 16 + lr) * 72 + kt * 32 + 8 * lg]);
        acc[rt] = __builtin_amdgcn_mfma_f32_16x16x32_bf16(ah, bh, acc[rt], 0, 0, 0);
        acc[rt] = __builtin_amdgcn_mfma_f32_16x16x32_bf16(al, bh, acc[rt], 0, 0, 0);
        acc[rt] = __builtin_amdgcn_mfma_f32_16x16x32_bf16(ah, bl, acc[rt], 0, 0, 0);
      }
    }
    __syncthreads();
  }
  int n = ctg * 16 + lr;
  float bs = bias[n];
  #pragma unroll
  for (int rt = 0; rt < 4; ++rt) {
    #pragma unroll
    for (int i = 0; i < 4; ++i) {
      int row = m0 + rt * 16 + lg * 4 + i;
      float v = acc[rt][i] + bs;
      if (n < reluN) v = fmaxf(v, 0.f);
      if (mode == 0) Cf[(size_t)row * N + n] = v;
      else {
        unsigned short h = f2b(v);
        Chi[(size_t)row * N + n] = h;
        Clo[(size_t)row * N + n] = f2b(v - b2f(h));
      }
    }
  }
}

// ---------------- fused entity + MFMA attention (swapped QK^T + MFMA PV) ----------------
// LDS 53,712 B -> 3 blocks/CU. Hand-packed overlays:
//   phase A: zh | qh kh xsP | vt | sah      phase B: P overlays qh/kh/xsP
__global__ __launch_bounds__(256, 3) void k_attn(
    const float* __restrict__ Pmat,
    const float* __restrict__ f0, const float* __restrict__ f1, const float* __restrict__ f2,
    const float* __restrict__ mk0, const float* __restrict__ mk1, const float* __restrict__ mk2,
    const unsigned short* __restrict__ WFF,
    const unsigned short* __restrict__ QKVF,
    const unsigned short* __restrict__ WOF,
    const unsigned short* __restrict__ WSAF,
    const float* __restrict__ ipb, const float* __restrict__ opb, const float* __restrict__ sab_,
    unsigned short* __restrict__ xch, unsigned short* __restrict__ xcl)
{
  __shared__ unsigned short smem[26856];        // 53,712 B
  unsigned short* zh  = smem;                   // [49][72]
  unsigned short* qh  = smem + 3528;            // [64][72] (phase A)
  unsigned short* kh  = smem + 8136;            // [64][72] (phase A)
  float*          xsP = (float*)(smem + 12744); // [256]    (phase A)
  unsigned short* pl  = smem + 3528;            // [4][49][72] P (phase B overlay)
  unsigned short* vt  = smem + 17640;           // [4][16][72] V^T
  unsigned short* sah = smem + 22248;           // [64][72] attn out
  unsigned short* oh  = kh;                     // [64][72] out_proj (phase C overlay)
  int m = blockIdx.x;
  int tid = threadIdx.x, w = tid >> 6, l = tid & 63;
  int lr = l & 15, lg = l >> 4;
  b8u zz;
  #pragma unroll
  for (int i = 0; i < 8; ++i) zz.u[i] = 0;
  bf16x8v zero8 = zz.b;

  // --- C0: P row -> xsP + zh row0; per-lane mask regs (key = rt*16+4*lg+ii) ---
  float mvr[16];
  {
    float pv = Pmat[(size_t)m * 256 + tid];
    xsP[tid] = pv;
    if (tid < 64) zh[tid] = f2b(pv);
    #pragma unroll
    for (int rt = 0; rt < 4; ++rt)
      #pragma unroll
      for (int ii = 0; ii < 4; ++ii) {
        int key = rt * 16 + 4 * lg + ii;
        float v;
        if (key == 0) v = 1.f;
        else if (key < 17) v = mk0[m * 16 + key - 1];
        else if (key < 33) v = mk1[m * 16 + key - 17];
        else if (key < 49) v = mk2[m * 16 + key - 33];
        else v = 0.f;
        mvr[rt * 4 + ii] = v;
      }
  }
  __syncthreads();

  // --- C1: entity rows 1..48 via MFMA (A = feats bf16 in-reg, B = WFF frags) ---
  {
    const float* fps[3] = {f0, f1, f2};
    #pragma unroll
    for (int t = 0; t < 3; ++t) {
      const int DK = (t == 0) ? 16 : (t == 1) ? 24 : 32;
      bf16x8v a;
      if (8 * lg < DK) {
        const float4* fr4 = reinterpret_cast<const float4*>(
            fps[t] + ((size_t)m * 16 + lr) * DK + 8 * lg);
        float4 fa = fr4[0], fb = fr4[1];
        b8u c;
        c.u[0] = f2b(fa.x); c.u[1] = f2b(fa.y); c.u[2] = f2b(fa.z); c.u[3] = f2b(fa.w);
        c.u[4] = f2b(fb.x); c.u[5] = f2b(fb.y); c.u[6] = f2b(fb.z); c.u[7] = f2b(fb.w);
        a = c.b;
      } else a = zero8;
      bf16x8v b = ld_bf8(&WFF[(t * 4 + w) * 512 + l * 8]);
      f32x4 acc = {0.f, 0.f, 0.f, 0.f};
      acc = __builtin_amdgcn_mfma_f32_16x16x32_bf16(a, b, acc, 0, 0, 0);
      int n = w * 16 + lr;
      float xb = xsP[64 + t * 64 + n];
      #pragma unroll
      for (int i = 0; i < 4; ++i) {
        int er = 4 * lg + i;
        zh[(1 + t * 16 + er) * 72 + n] = f2b(fmaxf(acc[i] + xb, 0.f));
      }
    }
  }
  __syncthreads();

  // --- C2: q,k,v = z @ Wqkv + b; k pre-scaled by 0.25 (exact pow2) ---
  {
    bf16x8v za[4][2];
    #pragma unroll
    for (int rt = 0; rt < 4; ++rt)
      #pragma unroll
      for (int kt = 0; kt < 2; ++kt) {
        bf16x8v t = ld_bf8(&zh[(rt * 16 + lr) * 72 + kt * 32 + 8 * lg]);  // rows>=49 alias qh: select zero
        za[rt][kt] = (rt * 16 + lr < 49) ? t : zero8;
      }
    #pragma unroll
    for (int cc = 0; cc < 3; ++cc) {
      int ct = w + 4 * cc;
      bf16x8v b0 = ld_bf8(&QKVF[((ct * 2 + 0) * 64 + l) * 8]);
      bf16x8v b1 = ld_bf8(&QKVF[((ct * 2 + 1) * 64 + l) * 8]);
      int n = ct * 16 + lr;
      float bias = ipb[n];
      #pragma unroll
      for (int rt = 0; rt < 4; ++rt) {
        f32x4 acc = {0.f, 0.f, 0.f, 0.f};
        acc = __builtin_amdgcn_mfma_f32_16x16x32_bf16(za[rt][0], b0, acc, 0, 0, 0);
        acc = __builtin_amdgcn_mfma_f32_16x16x32_bf16(za[rt][1], b1, acc, 0, 0, 0);
        #pragma unroll
        for (int i = 0; i < 4; ++i) {
          int r = rt * 16 + lg * 4 + i;
          float val = acc[i] + bias;
          if (cc == 0)      qh[r * 72 + n] = f2b(val);
          else if (cc == 1) kh[r * 72 + (n - 64)] = f2b(val * 0.25f);
          else { int hd = n - 128; vt[(hd >> 4) * 1152 + (hd & 15) * 72 + r] = f2b(val); }
        }
      }
    }
  }
  __syncthreads();

  // --- C3: S^T = K·Q^T (d 16->32 zero-pad), reg softmax, P->LDS, PV = V^T·P^T ---
  float pst[4][16];   // [ct][key-slot]: scores -> normalized probs
  {
    int h = w;
    bf16x8v ka[4], qb[4];
    #pragma unroll
    for (int rt = 0; rt < 4; ++rt) {
      bf16x8v t = ld_bf8(&kh[(rt * 16 + lr) * 72 + h * 16 + 8 * (lg & 1)]);
      ka[rt] = (lg < 2) ? t : zero8;          // k-chunks d16..31 are zero-pad
    }
    #pragma unroll
    for (int ct = 0; ct < 4; ++ct) {
      bf16x8v t = ld_bf8(&qh[(ct * 16 + lr) * 72 + h * 16 + 8 * (lg & 1)]);
      qb[ct] = (lg < 2) ? t : zero8;
    }
    #pragma unroll
    for (int ct = 0; ct < 4; ++ct)
      #pragma unroll
      for (int rt = 0; rt < 4; ++rt) {
        f32x4 acc = {0.f, 0.f, 0.f, 0.f};
        acc = __builtin_amdgcn_mfma_f32_16x16x32_bf16(ka[rt], qb[ct], acc, 0, 0, 0);
        #pragma unroll
        for (int i = 0; i < 4; ++i) pst[ct][rt * 4 + i] = acc[i];
      }
    // masked softmax per query q = ct*16+lr (keys spread over lg x regs); scale folded into k
    #pragma unroll
    for (int ct = 0; ct < 4; ++ct) {
      float mx = -1e30f;
      #pragma unroll
      for (int k16 = 0; k16 < 16; ++k16)
        if (mvr[k16] != 0.f) mx = fmaxf(mx, pst[ct][k16]);
      mx = fmaxf(mx, __shfl_xor(mx, 16, 64));
      mx = fmaxf(mx, __shfl_xor(mx, 32, 64));
      float sum = 0.f;
      #pragma unroll
      for (int k16 = 0; k16 < 16; ++k16) {
        float p = (mvr[k16] != 0.f) ? __expf(pst[ct][k16] - mx) : 0.f;
        pst[ct][k16] = p;
        sum += p;
      }
      sum += __shfl_xor(sum, 16, 64);
      sum += __shfl_xor(sum, 32, 64);
      float inv = 1.f / sum;
      #pragma unroll
      for (int k16 = 0; k16 < 16; ++k16) pst[ct][k16] *= inv;
    }
  }
  __syncthreads();                       // all qh/kh reads complete before P overlay
  {
    int h = w;
    unsigned short* ph = pl + h * 3528;  // [49][72]; rows>=49 unwritten (read-finite spill)
    #pragma unroll
    for (int ct = 0; ct < 4; ++ct) {
      int q = ct * 16 + lr;
      if (q < 49) {
        #pragma unroll
        for (int rt = 0; rt < 4; ++rt)
          #pragma unroll
          for (int ii = 0; ii < 4; ++ii)
            ph[q * 72 + rt * 16 + 4 * lg + ii] = f2b(pst[ct][rt * 4 + ii]);
      }
    }
  }
  __syncthreads();                       // P visible
  {
    int h = w;
    const unsigned short* ph = pl + h * 3528;
    bf16x8v va0 = ld_bf8(&vt[h * 1152 + lr * 72 + 8 * lg]);        // V^T[d=lr][keys 8lg..]
    bf16x8v va1 = ld_bf8(&vt[h * 1152 + lr * 72 + 32 + 8 * lg]);
    #pragma unroll
    for (int ct = 0; ct < 4; ++ct) {
      bf16x8v pb0 = ld_bf8(&ph[(ct * 16 + lr) * 72 + 8 * lg]);     // P^T[key][q=ct*16+lr]
      bf16x8v pb1 = ld_bf8(&ph[(ct * 16 + lr) * 72 + 32 + 8 * lg]);
      f32x4 o = {0.f, 0.f, 0.f, 0.f};
      o = __builtin_amdgcn_mfma_f32_16x16x32_bf16(va0, pb0, o, 0, 0, 0);
      o = __builtin_amdgcn_mfma_f32_16x16x32_bf16(va1, pb1, o, 0, 0, 0);
      int q = ct * 16 + lr;              // D[d=4*lg+i][q]
      #pragma unroll
      for (int i = 0; i < 4; ++i)
        sah[q * 72 + h * 16 + 4 * lg + i] = f2b(o[i]);
    }
  }
  __syncthreads();

  // --- C4: o = sa @ Wo + b (oh overlays kh; P dead) ---
  {
    int ct = w, n = ct * 16 + lr;
    bf16x8v b0 = ld_bf8(&WOF[((ct * 2 + 0) * 64 + l) * 8]);
    bf16x8v b1 = ld_bf8(&WOF[((ct * 2 + 1) * 64 + l) * 8]);
    float bias = opb[n];
    #pragma unroll
    for (int rt = 0; rt < 4; ++rt) {
      bf16x8v a0 = ld_bf8(&sah[(rt * 16 + lr) * 72 + 8 * lg]);
      bf16x8v a1 = ld_bf8(&sah[(rt * 16 + lr) * 72 + 32 + 8 * lg]);
      f32x4 acc = {0.f, 0.f, 0.f, 0.f};
      acc = __builtin_amdgcn_mfma_f32_16x16x32_bf16(a0, b0, acc, 0, 0, 0);
      acc = __builtin_amdgcn_mfma_f32_16x16x32_bf16(a1, b1, acc, 0, 0, 0);
      #pragma unroll
      for (int i = 0; i < 4; ++i) {
        int r = rt * 16 + lg * 4 + i;
        if (r < 49) oh[r * 72 + n] = f2b(acc[i] + bias);
      }
    }
  }
  __syncthreads();

  // --- C5: res = z + relu(o @ Wsa + b); masked mean (mvr regs); split-bf16 out ---
  {
    int ct = w, n = ct * 16 + lr;
    bf16x8v b0 = ld_bf8(&WSAF[((ct * 2 + 0) * 64 + l) * 8]);
    bf16x8v b1 = ld_bf8(&WSAF[((ct * 2 + 1) * 64 + l) * 8]);
    float bias = sab_[n];
    float pacc = 0.f;
    #pragma unroll
    for (int rt = 0; rt < 4; ++rt) {
      bf16x8v a0 = ld_bf8(&oh[(rt * 16 + lr) * 72 + 8 * lg]);
      bf16x8v a1 = ld_bf8(&oh[(rt * 16 + lr) * 72 + 32 + 8 * lg]);
      f32x4 acc = {0.f, 0.f, 0.f, 0.f};
      acc = __builtin_amdgcn_mfma_f32_16x16x32_bf16(a0, b0, acc, 0, 0, 0);
      acc = __builtin_amdgcn_mfma_f32_16x16x32_bf16(a1, b1, acc, 0, 0, 0);
      #pragma unroll
      for (int i = 0; i < 4; ++i) {
        int r = rt * 16 + lg * 4 + i;
        if (r < 49) {
          float val = fmaxf(acc[i] + bias, 0.f);
          float z = b2f(zh[r * 72 + n]);
          pacc += (z + val) * mvr[rt * 4 + i];   // mvr slot key == r
        }
      }
    }
    pacc += __shfl_xor(pacc, 16, 64);
    pacc += __shfl_xor(pacc, 32, 64);
    if (lg == 0) {
      float y = pacc * (1.0f / 49.0f);
      unsigned short h = f2b(y);
      xch[(size_t)m * 384 + 290 + n] = h;
      xcl[(size_t)m * 384 + 290 + n] = f2b(y - b2f(h));
    }
  }
}

// ---------------- LSTM scan + value head (Gx prefetch) ----------------
__global__ __launch_bounds__(512) void k_lstm(
    const float* __restrict__ Gx, const float* __restrict__ whh,
    const float* __restrict__ done, const float* __restrict__ h0, const float* __restrict__ c0,
    const float* __restrict__ hw, const float* __restrict__ hb, float* __restrict__ out)
{
  __shared__ float h[128], c[128], gl[512], red[2];
  int s = blockIdx.x, b = s >> 3;
  int g = threadIdx.x;
  float wreg[128];
  {
    const float4* w4 = reinterpret_cast<const float4*>(whh + (size_t)g * 128);
    #pragma unroll
    for (int j4 = 0; j4 < 32; ++j4) {
      float4 f4 = w4[j4];
      wreg[4 * j4] = f4.x; wreg[4 * j4 + 1] = f4.y; wreg[4 * j4 + 2] = f4.z; wreg[4 * j4 + 3] = f4.w;
    }
  }
  if (g < 128) { h[g] = h0[s * 128 + g]; c[g] = c0[s * 128 + g]; }
  float gx = Gx[(size_t)s * 512 + g];           // t = 0
  __syncthreads();
  for (int t = 0; t < 32; ++t) {
    float gx_nxt = (t < 31) ? Gx[(size_t)((t + 1) * 128 + s) * 512 + g] : 0.f;
    float keep = 1.f - done[t * 16 + b];
    float acc = 0.f;
    const float4* h4 = reinterpret_cast<const float4*>(h);
    #pragma unroll
    for (int j4 = 0; j4 < 32; ++j4) {
      float4 f4 = h4[j4];
      acc += f4.x * wreg[4 * j4] + f4.y * wreg[4 * j4 + 1] + f4.z * wreg[4 * j4 + 2] + f4.w * wreg[4 * j4 + 3];
    }
    gl[g] = gx + keep * acc;
    __syncthreads();
    if (g < 128) {
      float iv = sigf(gl[g]);
      float fv = sigf(gl[128 + g]);
      float gg = tanhf(gl[256 + g]);
      float ov = sigf(gl[384 + g]);
      float cn = fv * (c[g] * keep) + iv * gg;
      float hn = ov * tanhf(cn);
      c[g] = cn; h[g] = hn;
      float pv = hn * hw[g];
      #pragma unroll
      for (int off = 32; off > 0; off >>= 1) pv += __shfl_down(pv, off, 64);
      if ((g & 63) == 0) red[g >> 6] = pv;
    }
    __syncthreads();
    if (g == 0) out[t * 128 + s] = red[0] + red[1] + hb[0];
    gx = gx_nxt;
  }
}

// ---------------- launch ----------------
extern "C" void kernel_launch(void* const* d_in, const int* in_sizes, int n_in,
                              void* d_out, int out_size, void* d_ws, size_t ws_size,
                              hipStream_t stream) {
  const float* x_agent = (const float*)d_in[0];
  const float* x_lidar = (const float*)d_in[1];
  const float* x_safe  = (const float*)d_in[2];
  const float* ef0 = (const float*)d_in[3];
  const float* em0 = (const float*)d_in[4];
  const float* ef1 = (const float*)d_in[5];
  const float* em1 = (const float*)d_in[6];
  const float* ef2 = (const float*)d_in[7];
  const float* em2 = (const float*)d_in[8];
  const float* done = (const float*)d_in[9];
  const float* h0 = (const float*)d_in[10];
  const float* c0 = (const float*)d_in[11];
  const float* lw = (const float*)d_in[12];
  const float* lb = (const float*)d_in[13];
  const float* self_w = (const float*)d_in[14];
  const float* self_b = (const float*)d_in[15];
  const float* e0w = (const float*)d_in[16];
  const float* e0b = (const float*)d_in[17];
  const float* e1w = (const float*)d_in[18];
  const float* e1b = (const float*)d_in[19];
  const float* e2w = (const float*)d_in[20];
  const float* e2b = (const float*)d_in[21];
  const float* ipw = (const float*)d_in[22];
  const float* ipb = (const float*)d_in[23];
  const float* opw = (const float*)d_in[24];
  const float* opb = (const float*)d_in[25];
  const float* saw = (const float*)d_in[26];
  const float* sab = (const float*)d_in[27];
  const float* plw = (const float*)d_in[28];
  const float* plb = (const float*)d_in[29];
  const float* wih = (const float*)d_in[30];
  const float* whh = (const float*)d_in[31];
  const float* bih = (const float*)d_in[32];
  const float* bhh = (const float*)d_in[33];
  const float* hw  = (const float*)d_in[34];
  const float* hb  = (const float*)d_in[35];
  float* ws  = (float*)d_ws;
  float* out = (float*)d_out;

  unsigned short* XCH = (unsigned short*)(ws + XCH_OFF);
  unsigned short* XCL = (unsigned short*)(ws + XCL_OFF);

  k_prep<<<256, 256, 0, stream>>>(self_w, self_b, e0w, e0b, e1w, e1b, e2w, e2b,
                                  ipw, opw, saw, plw, wih, bih, bhh, ws);
  k_assemble<<<2048, 256, 0, stream>>>(x_agent, x_lidar, x_safe, lw, lb, XCH, XCL);
  {
    dim3 g(64, 4);   // P = XC(:, :290) @ WP + bP; relu on cols < 64
    k_bgemm<<<g, 256, 0, stream>>>(XCH, XCL, 384,
                                   (const unsigned short*)(ws + WPH_OFF),
                                   (const unsigned short*)(ws + WPL_OFF),
                                   ws + BP_OFF, 320, 256, 64,
                                   ws + P_OFF, nullptr, nullptr, 0);
  }
  k_attn<<<4096, 256, 0, stream>>>(ws + P_OFF, ef0, ef1, ef2, em0, em1, em2,
                                   (const unsigned short*)(ws + WF_OFF),
                                   (const unsigned short*)(ws + QKV_OFF),
                                   (const unsigned short*)(ws + WO_OFF),
                                   (const unsigned short*)(ws + WSA_OFF),
                                   ipb, opb, sab, XCH, XCL);
  {
    dim3 g(64, 2);   // Z = relu([X | z_pool] @ plw^T + plb), split-bf16 out
    k_bgemm<<<g, 256, 0, stream>>>(XCH, XCL, 384,
                                   (const unsigned short*)(ws + PWH_OFF),
                                   (const unsigned short*)(ws + PWL_OFF),
                                   plb, 384, 128, 128,
                                   nullptr,
                                   (unsigned short*)(ws + ZH_OFF),
                                   (unsigned short*)(ws + ZL_OFF), 1);
  }
  {
    dim3 g(64, 8);   // Gx = Z @ w_ih^T + (b_ih + b_hh), fp32 out
    k_bgemm<<<g, 256, 0, stream>>>((const unsigned short*)(ws + ZH_OFF),
                                   (const unsigned short*)(ws + ZL_OFF), 128,
                                   (const unsigned short*)(ws + WIHH_OFF),
                                   (const unsigned short*)(ws + WIHL_OFF),
                                   ws + BG_OFF, 128, 512, 0,
                                   ws + GX_OFF, nullptr, nullptr, 0);
  }
  k_lstm<<<128, 512, 0, stream>>>(ws + GX_OFF, whh, done, h0, c0, hw, hb, out);
}